// Round 8
// baseline (3763.163 us; speedup 1.0000x reference)
//
#include <hip/hip_runtime.h>

#define DIM 64

typedef __attribute__((ext_vector_type(4))) float f4;
typedef __attribute__((ext_vector_type(2))) float f2;
typedef __attribute__((ext_vector_type(4))) unsigned int u4;
typedef __attribute__((ext_vector_type(2))) unsigned int u2;

#define SEL_LO 0x01000504u   // [src0.lo16 | src1.lo16<<16]
#define SEL_HI 0x03020706u   // [src0.hi16 | src1.hi16<<16]
#define ONE2   0x3f803f80u   // bf16 pair (1.0, 1.0)

// ---- bf16 helpers ----
__device__ __forceinline__ float bflo(unsigned u) { return __uint_as_float(u << 16); }
__device__ __forceinline__ float bfhi(unsigned u) { return __uint_as_float(u & 0xffff0000u); }
__device__ __forceinline__ unsigned bfr(float f) {
    unsigned u = __float_as_uint(f);
    return (u + 0x7fffu + ((u >> 16) & 1u)) >> 16;
}
__device__ __forceinline__ unsigned packbf(float e, float o) { return bfr(e) | (bfr(o) << 16); }
__device__ __forceinline__ unsigned cvtpk(float lo, float hi) {
    unsigned r;
    asm("v_cvt_pk_bf16_f32 %0, %1, %2" : "=v"(r) : "v"(lo), "v"(hi));
    return r;
}
__device__ __forceinline__ float dot2bf(unsigned a, unsigned b, float c) {
    float d;
    asm("v_dot2_f32_bf16 %0, %1, %2, %3" : "=v"(d) : "v"(a), "v"(b), "v"(c));
    return d;
}
__device__ __forceinline__ float gsum8(float v) {
    v += __shfl_xor(v, 1, 64);
    v += __shfl_xor(v, 2, 64);
    v += __shfl_xor(v, 4, 64);
    return v;
}

// row_ptr[r] = lower_bound(rows, r) over sorted rows.
__global__ void build_row_ptr_kernel(const int* __restrict__ rows, int nnz,
                                     int n, int* __restrict__ row_ptr) {
    int r = blockIdx.x * blockDim.x + threadIdx.x;
    if (r > n) return;
    int lo = 0, hi = nnz;
    while (lo < hi) {
        int mid = (lo + hi) >> 1;
        if (rows[mid] < r) lo = mid + 1; else hi = mid;
    }
    row_ptr[r] = lo;
}

// f32 -> packed bf16 table, 8 elems per thread.
__global__ void cvt_bf16_kernel(const float* __restrict__ in,
                                unsigned int* __restrict__ out, int n8) {
    int i = blockIdx.x * blockDim.x + threadIdx.x;
    if (i >= n8) return;
    const f4* p = (const f4*)in + 2 * (size_t)i;
    f4 a = p[0], b = p[1];
    u4 o;
    o.x = packbf(a.x, a.y); o.y = packbf(a.z, a.w);
    o.z = packbf(b.x, b.y); o.w = packbf(b.z, b.w);
    ((u4*)out)[i] = o;
}

// ---- length counting-sort (64 bins) ----
__global__ void zero_hist_kernel(int* __restrict__ h) { h[threadIdx.x] = 0; }

__global__ void len_hist_kernel(const int* __restrict__ rp, int n,
                                int* __restrict__ hist) {
    int r = blockIdx.x * blockDim.x + threadIdx.x;
    if (r >= n) return;
    int len = rp[r + 1] - rp[r]; if (len > 63) len = 63;
    atomicAdd(hist + len, 1);
}

// descending-length exclusive offsets (serial over 64 bins)
__global__ void scan_hist_kernel(const int* __restrict__ hist,
                                 int* __restrict__ cursor) {
    if (threadIdx.x == 0) {
        int off = 0;
        for (int L = 63; L >= 0; --L) { cursor[L] = off; off += hist[L]; }
    }
}

__global__ void scatter_perm_kernel(const int* __restrict__ rp, int n,
                                    int* __restrict__ cursor,
                                    int* __restrict__ perm) {
    int r = blockIdx.x * blockDim.x + threadIdx.x;
    if (r >= n) return;
    int len = rp[r + 1] - rp[r]; if (len > 63) len = 63;
    int pos = atomicAdd(cursor + len, 1);
    perm[pos] = r;
}

// One ROW per 8-lane group (8 rows/wave), rows assigned via length-sorted
// perm so wave-max length ~= avg length (no padded gather waste).
// MODE 0: e1 = A1 @ t0 -> enew; y-stats (my,svy) -> stats; b1 -> bbuf
// MODE 1: prop = A2@eprev; en = b*prop+(1-b)*t0 -> enew; b_next -> bbuf
// MODE 2: en with y0 = emb(f32); out = (emb + e1 + e2 + eprev + en)/5
template <int MODE>
__global__ __launch_bounds__(256) void layer_kernel(
    const float* __restrict__ emb,
    const unsigned short* __restrict__ t0,
    const unsigned short* __restrict__ eprev,
    const float* __restrict__ vals, const int* __restrict__ cols,
    const int* __restrict__ rp, const int* __restrict__ perm, int n,
    unsigned short* __restrict__ enew,
    const unsigned short* __restrict__ e1t,
    const unsigned short* __restrict__ e2t,
    f2* __restrict__ stats, float* __restrict__ bbuf,
    float* __restrict__ out)
{
    const int tid  = threadIdx.x;
    const int lane = tid & 63;
    const int j    = lane & 7;
    const int wave = blockIdx.x * (blockDim.x >> 6) + (tid >> 6);
    const int vi   = wave * 8 + (lane >> 3);         // virtual (sorted) index
    const bool valid = vi < n;
    const int rg   = perm[valid ? vi : n - 1];       // actual row id

    const int start = rp[rg];
    const int end   = rp[rg + 1];
    const int len   = valid ? (end - start) : 0;
    const int b0    = start & ~1;
    const int doff  = b0 - start;

    int ml = len;
    ml = max(ml, __shfl_xor(ml, 8, 64));
    ml = max(ml, __shfl_xor(ml, 16, 64));
    ml = max(ml, __shfl_xor(ml, 32, 64));
    const int steps = (ml + 8) >> 3;

    const char* tb8 = (const char*)eprev;
    const unsigned joff = (unsigned)(j << 4);
    const size_t ro = (size_t)rg << 6;

    // early loads (hide latency under the main loop)
    float bcoef = 0.f;
    if (MODE != 0) bcoef = bbuf[rg];
    u4 yr = {};
    if (MODE != 2) yr = *((const u4*)(t0 + ro) + j);
    f2 st = {};
    if (MODE == 1) st = stats[rg];

    float acc[8] = {0.f, 0.f, 0.f, 0.f, 0.f, 0.f, 0.f, 0.f};

    for (int s = 0; s < steps; ++s) {
        const int k = b0 + (s << 3);
        u2 c01 = __builtin_nontemporal_load((const u2*)(cols + k));
        u2 c23 = __builtin_nontemporal_load((const u2*)(cols + k + 2));
        u2 c45 = __builtin_nontemporal_load((const u2*)(cols + k + 4));
        u2 c67 = __builtin_nontemporal_load((const u2*)(cols + k + 6));
        f2 v01 = __builtin_nontemporal_load((const f2*)(vals + k));
        f2 v23 = __builtin_nontemporal_load((const f2*)(vals + k + 2));
        f2 v45 = __builtin_nontemporal_load((const f2*)(vals + k + 4));
        f2 v67 = __builtin_nontemporal_load((const f2*)(vals + k + 6));
        const int rel = (s << 3) + doff;
        bool ok0 = (unsigned)(rel)     < (unsigned)len;
        bool ok1 = (unsigned)(rel + 1) < (unsigned)len;
        bool ok2 = (unsigned)(rel + 2) < (unsigned)len;
        bool ok3 = (unsigned)(rel + 3) < (unsigned)len;
        bool ok4 = (unsigned)(rel + 4) < (unsigned)len;
        bool ok5 = (unsigned)(rel + 5) < (unsigned)len;
        bool ok6 = (unsigned)(rel + 6) < (unsigned)len;
        bool ok7 = (unsigned)(rel + 7) < (unsigned)len;
        unsigned cc0 = ok0 ? (unsigned)c01.x : 0u;
        unsigned cc1 = ok1 ? (unsigned)c01.y : 0u;
        unsigned cc2 = ok2 ? (unsigned)c23.x : 0u;
        unsigned cc3 = ok3 ? (unsigned)c23.y : 0u;
        unsigned cc4 = ok4 ? (unsigned)c45.x : 0u;
        unsigned cc5 = ok5 ? (unsigned)c45.y : 0u;
        unsigned cc6 = ok6 ? (unsigned)c67.x : 0u;
        unsigned cc7 = ok7 ? (unsigned)c67.y : 0u;
        u4 g0 = *(const u4*)(tb8 + ((cc0 << 7) + joff));
        u4 g1 = *(const u4*)(tb8 + ((cc1 << 7) + joff));
        u4 g2 = *(const u4*)(tb8 + ((cc2 << 7) + joff));
        u4 g3 = *(const u4*)(tb8 + ((cc3 << 7) + joff));
        u4 g4 = *(const u4*)(tb8 + ((cc4 << 7) + joff));
        u4 g5 = *(const u4*)(tb8 + ((cc5 << 7) + joff));
        u4 g6 = *(const u4*)(tb8 + ((cc6 << 7) + joff));
        u4 g7 = *(const u4*)(tb8 + ((cc7 << 7) + joff));
        float w0 = ok0 ? v01.x : 0.f;
        float w1 = ok1 ? v01.y : 0.f;
        float w2 = ok2 ? v23.x : 0.f;
        float w3 = ok3 ? v23.y : 0.f;
        float w4 = ok4 ? v45.x : 0.f;
        float w5 = ok5 ? v45.y : 0.f;
        float w6 = ok6 ? v67.x : 0.f;
        float w7 = ok7 ? v67.y : 0.f;
        unsigned vp01 = cvtpk(w0, w1);
        unsigned vp23 = cvtpk(w2, w3);
        unsigned vp45 = cvtpk(w4, w5);
        unsigned vp67 = cvtpk(w6, w7);
#define CONSUME(ga, gb, vp)                                                    \
        acc[0] = dot2bf(__builtin_amdgcn_perm(ga.x, gb.x, SEL_LO), vp, acc[0]);\
        acc[1] = dot2bf(__builtin_amdgcn_perm(ga.x, gb.x, SEL_HI), vp, acc[1]);\
        acc[2] = dot2bf(__builtin_amdgcn_perm(ga.y, gb.y, SEL_LO), vp, acc[2]);\
        acc[3] = dot2bf(__builtin_amdgcn_perm(ga.y, gb.y, SEL_HI), vp, acc[3]);\
        acc[4] = dot2bf(__builtin_amdgcn_perm(ga.z, gb.z, SEL_LO), vp, acc[4]);\
        acc[5] = dot2bf(__builtin_amdgcn_perm(ga.z, gb.z, SEL_HI), vp, acc[5]);\
        acc[6] = dot2bf(__builtin_amdgcn_perm(ga.w, gb.w, SEL_LO), vp, acc[6]);\
        acc[7] = dot2bf(__builtin_amdgcn_perm(ga.w, gb.w, SEL_HI), vp, acc[7]);
        CONSUME(g0, g1, vp01)
        CONSUME(g2, g3, vp23)
        CONSUME(g4, g5, vp45)
        CONSUME(g6, g7, vp67)
#undef CONSUME
    }

    if (MODE == 0) {
        float sy  = dot2bf(yr.x, ONE2,
                    dot2bf(yr.y, ONE2, dot2bf(yr.z, ONE2, dot2bf(yr.w, ONE2, 0.f))));
        float syy = dot2bf(yr.x, yr.x,
                    dot2bf(yr.y, yr.y, dot2bf(yr.z, yr.z, dot2bf(yr.w, yr.w, 0.f))));
        sy = gsum8(sy); syy = gsum8(syy);
        float my  = sy * (1.f / 64.f);
        float vy  = syy - sy * my;
        float svy = sqrtf(fmaxf(vy, 0.f));
        u4 o;
        o.x = cvtpk(acc[0], acc[1]); o.y = cvtpk(acc[2], acc[3]);
        o.z = cvtpk(acc[4], acc[5]); o.w = cvtpk(acc[6], acc[7]);
        float sx  = dot2bf(o.x, ONE2,
                    dot2bf(o.y, ONE2, dot2bf(o.z, ONE2, dot2bf(o.w, ONE2, 0.f))));
        float sxx = dot2bf(o.x, o.x,
                    dot2bf(o.y, o.y, dot2bf(o.z, o.z, dot2bf(o.w, o.w, 0.f))));
        float sxy = dot2bf(o.x, yr.x,
                    dot2bf(o.y, yr.y, dot2bf(o.z, yr.z, dot2bf(o.w, yr.w, 0.f))));
        sx = gsum8(sx); sxx = gsum8(sxx); sxy = gsum8(sxy);
        float mx  = sx * (1.f / 64.f);
        float num = sxy - sx * my;
        float vx  = sxx - sx * mx;
        float den = sqrtf(fmaxf(vx, 0.f)) * svy;
        den = fmaxf(den, 1e-7f);
        float bn = num / den;
        if (valid) {
            if (j == 0) {
                f2 s2; s2.x = my; s2.y = svy;
                stats[rg] = s2;
                bbuf[rg]  = bn;
            }
            *((u4*)(enew + ro) + j) = o;
        }
        return;
    }

    const float ob = 1.f - bcoef;

    if (MODE == 1) {
        float y0[8] = { bflo(yr.x), bfhi(yr.x), bflo(yr.y), bfhi(yr.y),
                        bflo(yr.z), bfhi(yr.z), bflo(yr.w), bfhi(yr.w) };
        u4 o;
        o.x = cvtpk(bcoef * acc[0] + ob * y0[0], bcoef * acc[1] + ob * y0[1]);
        o.y = cvtpk(bcoef * acc[2] + ob * y0[2], bcoef * acc[3] + ob * y0[3]);
        o.z = cvtpk(bcoef * acc[4] + ob * y0[4], bcoef * acc[5] + ob * y0[5]);
        o.w = cvtpk(bcoef * acc[6] + ob * y0[6], bcoef * acc[7] + ob * y0[7]);
        float sx  = dot2bf(o.x, ONE2,
                    dot2bf(o.y, ONE2, dot2bf(o.z, ONE2, dot2bf(o.w, ONE2, 0.f))));
        float sxx = dot2bf(o.x, o.x,
                    dot2bf(o.y, o.y, dot2bf(o.z, o.z, dot2bf(o.w, o.w, 0.f))));
        float sxy = dot2bf(o.x, yr.x,
                    dot2bf(o.y, yr.y, dot2bf(o.z, yr.z, dot2bf(o.w, yr.w, 0.f))));
        sx = gsum8(sx); sxx = gsum8(sxx); sxy = gsum8(sxy);
        float mx  = sx * (1.f / 64.f);
        float num = sxy - sx * st.x;
        float vx  = sxx - sx * mx;
        float den = sqrtf(fmaxf(vx, 0.f)) * st.y;
        den = fmaxf(den, 1e-7f);
        float bn = num / den;
        if (valid) {
            if (j == 0) bbuf[rg] = bn;
            *((u4*)(enew + ro) + j) = o;
        }
    } else {
        const f4* ep = (const f4*)(emb + ro) + 2 * j;
        f4 ea = ep[0], eb = ep[1];
        float y0[8] = { ea.x, ea.y, ea.z, ea.w, eb.x, eb.y, eb.z, eb.w };
        u4 xr = *((const u4*)(eprev + ro) + j);
        float xp[8] = { bflo(xr.x), bfhi(xr.x), bflo(xr.y), bfhi(xr.y),
                        bflo(xr.z), bfhi(xr.z), bflo(xr.w), bfhi(xr.w) };
        u4 r1 = *((const u4*)(e1t + ro) + j);
        u4 r2 = *((const u4*)(e2t + ro) + j);
        float s[8];
        s[0] = y0[0] + bflo(r1.x) + bflo(r2.x) + xp[0] + (bcoef * acc[0] + ob * y0[0]);
        s[1] = y0[1] + bfhi(r1.x) + bfhi(r2.x) + xp[1] + (bcoef * acc[1] + ob * y0[1]);
        s[2] = y0[2] + bflo(r1.y) + bflo(r2.y) + xp[2] + (bcoef * acc[2] + ob * y0[2]);
        s[3] = y0[3] + bfhi(r1.y) + bfhi(r2.y) + xp[3] + (bcoef * acc[3] + ob * y0[3]);
        s[4] = y0[4] + bflo(r1.z) + bflo(r2.z) + xp[4] + (bcoef * acc[4] + ob * y0[4]);
        s[5] = y0[5] + bfhi(r1.z) + bfhi(r2.z) + xp[5] + (bcoef * acc[5] + ob * y0[5]);
        s[6] = y0[6] + bflo(r1.w) + bflo(r2.w) + xp[6] + (bcoef * acc[6] + ob * y0[6]);
        s[7] = y0[7] + bfhi(r1.w) + bfhi(r2.w) + xp[7] + (bcoef * acc[7] + ob * y0[7]);
        if (valid) {
            f4 o0 = { s[0] * 0.2f, s[1] * 0.2f, s[2] * 0.2f, s[3] * 0.2f };
            f4 o1 = { s[4] * 0.2f, s[5] * 0.2f, s[6] * 0.2f, s[7] * 0.2f };
            f4* op = (f4*)(out + ro) + 2 * j;
            op[0] = o0; op[1] = o1;
        }
    }
}

extern "C" void kernel_launch(void* const* d_in, const int* in_sizes, int n_in,
                              void* d_out, int out_size, void* d_ws, size_t ws_size,
                              hipStream_t stream) {
    const float* emb   = (const float*)d_in[0];
    const float* vals  = (const float*)d_in[1];
    const float* vals2 = (const float*)d_in[2];
    const int*   rows  = (const int*)d_in[3];
    const int*   cols  = (const int*)d_in[4];
    const int*   rows2 = (const int*)d_in[5];
    const int*   cols2 = (const int*)d_in[6];
    // n_layers = 3 (fixed for this problem)

    const int n    = in_sizes[0] / DIM;   // 300000
    const int nnz  = in_sizes[1];         // 4800000
    const int nnz2 = in_sizes[2];

    float* out = (float*)d_out;

    // ws: rp1 | rp2 | ST | BB | P1 | P2 | HIST(2x64+2x64) | T0 | E1 | E2 | E3
    char*  ws       = (char*)d_ws;
    size_t rp_bytes = (((size_t)(n + 1) * sizeof(int)) + 255) & ~(size_t)255;
    size_t st_bytes = (((size_t)n * sizeof(f2)) + 255) & ~(size_t)255;
    size_t bb_bytes = (((size_t)n * sizeof(float)) + 255) & ~(size_t)255;
    size_t pm_bytes = (((size_t)n * sizeof(int)) + 255) & ~(size_t)255;
    size_t tb_bytes = (size_t)n * DIM * sizeof(unsigned short);
    int*   rp1 = (int*)ws;
    int*   rp2 = (int*)(ws + rp_bytes);
    f2*    ST  = (f2*)(ws + 2 * rp_bytes);
    float* BB  = (float*)(ws + 2 * rp_bytes + st_bytes);
    int*   P1  = (int*)(ws + 2 * rp_bytes + st_bytes + bb_bytes);
    int*   P2  = (int*)((char*)P1 + pm_bytes);
    int*   HIST = (int*)((char*)P2 + pm_bytes);        // h1[64] h2[64] c1[64] c2[64]
    int*   H1 = HIST, *H2 = HIST + 64, *C1 = HIST + 128, *C2 = HIST + 192;
    unsigned short* T0 = (unsigned short*)((char*)HIST + 1024);
    unsigned short* E1 = (unsigned short*)((char*)T0 + tb_bytes);
    unsigned short* E2 = (unsigned short*)((char*)E1 + tb_bytes);
    unsigned short* E3 = (unsigned short*)((char*)E2 + tb_bytes);

    const int tb = 256;
    build_row_ptr_kernel<<<(n + 1 + tb - 1) / tb, tb, 0, stream>>>(rows,  nnz,  n, rp1);
    build_row_ptr_kernel<<<(n + 1 + tb - 1) / tb, tb, 0, stream>>>(rows2, nnz2, n, rp2);

    const int n8 = n * DIM / 8;
    cvt_bf16_kernel<<<(n8 + tb - 1) / tb, tb, 0, stream>>>(emb, (unsigned int*)T0, n8);

    // length counting-sort -> P1 (rp1), P2 (rp2)
    zero_hist_kernel<<<1, 128, 0, stream>>>(HIST);     // h1,h2
    len_hist_kernel<<<(n + tb - 1) / tb, tb, 0, stream>>>(rp1, n, H1);
    len_hist_kernel<<<(n + tb - 1) / tb, tb, 0, stream>>>(rp2, n, H2);
    scan_hist_kernel<<<1, 64, 0, stream>>>(H1, C1);
    scan_hist_kernel<<<1, 64, 0, stream>>>(H2, C2);
    scatter_perm_kernel<<<(n + tb - 1) / tb, tb, 0, stream>>>(rp1, n, C1, P1);
    scatter_perm_kernel<<<(n + tb - 1) / tb, tb, 0, stream>>>(rp2, n, C2, P2);

    const int waves = (n + 7) / 8;            // 8 rows per wave
    const int grid  = (waves + 3) / 4;        // 4 waves per 256-thread block
    layer_kernel<0><<<grid, tb, 0, stream>>>(emb, T0, T0, vals, cols, rp1, P1, n,
                                             E1, T0, T0, ST, BB, out);
    layer_kernel<1><<<grid, tb, 0, stream>>>(emb, T0, E1, vals2, cols2, rp2, P2, n,
                                             E2, T0, T0, ST, BB, out);
    layer_kernel<1><<<grid, tb, 0, stream>>>(emb, T0, E2, vals2, cols2, rp2, P2, n,
                                             E3, T0, T0, ST, BB, out);
    layer_kernel<2><<<grid, tb, 0, stream>>>(emb, T0, E3, vals2, cols2, rp2, P2, n,
                                             E3, E1, E2, ST, BB, out);
}

// Round 9
// 671.729 us; speedup vs baseline: 5.6022x; 5.6022x over previous
//
#include <hip/hip_runtime.h>

#define DIM 64

typedef __attribute__((ext_vector_type(4))) float f4;
typedef __attribute__((ext_vector_type(2))) float f2;
typedef __attribute__((ext_vector_type(4))) unsigned int u4;
typedef __attribute__((ext_vector_type(2))) unsigned int u2;

#define SEL_LO 0x01000504u   // [src0.lo16 | src1.lo16<<16]
#define SEL_HI 0x03020706u   // [src0.hi16 | src1.hi16<<16]
#define ONE2   0x3f803f80u   // bf16 pair (1.0, 1.0)

// ---- bf16 helpers ----
__device__ __forceinline__ float bflo(unsigned u) { return __uint_as_float(u << 16); }
__device__ __forceinline__ float bfhi(unsigned u) { return __uint_as_float(u & 0xffff0000u); }
__device__ __forceinline__ unsigned bfr(float f) {
    unsigned u = __float_as_uint(f);
    return (u + 0x7fffu + ((u >> 16) & 1u)) >> 16;
}
__device__ __forceinline__ unsigned packbf(float e, float o) { return bfr(e) | (bfr(o) << 16); }
__device__ __forceinline__ unsigned cvtpk(float lo, float hi) {
    unsigned r;
    asm("v_cvt_pk_bf16_f32 %0, %1, %2" : "=v"(r) : "v"(lo), "v"(hi));
    return r;
}
__device__ __forceinline__ float dot2bf(unsigned a, unsigned b, float c) {
    float d;
    asm("v_dot2_f32_bf16 %0, %1, %2, %3" : "=v"(d) : "v"(a), "v"(b), "v"(c));
    return d;
}
__device__ __forceinline__ float gsum8(float v) {
    v += __shfl_xor(v, 1, 64);
    v += __shfl_xor(v, 2, 64);
    v += __shfl_xor(v, 4, 64);
    return v;
}

// row_ptr[r] = lower_bound(rows, r) over sorted rows.
__global__ void build_row_ptr_kernel(const int* __restrict__ rows, int nnz,
                                     int n, int* __restrict__ row_ptr) {
    int r = blockIdx.x * blockDim.x + threadIdx.x;
    if (r > n) return;
    int lo = 0, hi = nnz;
    while (lo < hi) {
        int mid = (lo + hi) >> 1;
        if (rows[mid] < r) lo = mid + 1; else hi = mid;
    }
    row_ptr[r] = lo;
}

// f32 -> packed bf16 table, 8 elems per thread.
__global__ void cvt_bf16_kernel(const float* __restrict__ in,
                                unsigned int* __restrict__ out, int n8) {
    int i = blockIdx.x * blockDim.x + threadIdx.x;
    if (i >= n8) return;
    const f4* p = (const f4*)in + 2 * (size_t)i;
    f4 a = p[0], b = p[1];
    u4 o;
    o.x = packbf(a.x, a.y); o.y = packbf(a.z, a.w);
    o.z = packbf(b.x, b.y); o.w = packbf(b.z, b.w);
    ((u4*)out)[i] = o;
}

// ---- block-aggregated length counting-sort (64 bins) ----
__global__ void zero_hist_kernel(int* __restrict__ h) { h[threadIdx.x] = 0; }

// phase 1: per-block LDS histogram -> 1 global atomic per (block,bin)
__global__ __launch_bounds__(256) void hist_kernel(
    const int* __restrict__ rp, int n, int* __restrict__ hist) {
    __shared__ int h[64];
    if (threadIdx.x < 64) h[threadIdx.x] = 0;
    __syncthreads();
    int r = blockIdx.x * blockDim.x + threadIdx.x;
    if (r < n) {
        int len = rp[r + 1] - rp[r]; if (len > 63) len = 63;
        atomicAdd(h + len, 1);
    }
    __syncthreads();
    if (threadIdx.x < 64 && h[threadIdx.x] > 0)
        atomicAdd(hist + threadIdx.x, h[threadIdx.x]);
}

// phase 2: descending-length exclusive bin bases -> cursor
__global__ void scan_hist_kernel(const int* __restrict__ hist,
                                 int* __restrict__ cursor) {
    if (threadIdx.x == 0) {
        int off = 0;
        for (int L = 63; L >= 0; --L) { cursor[L] = off; off += hist[L]; }
    }
}

// phase 3: per-block base via 1 atomic per (block,bin) + LDS local rank
__global__ __launch_bounds__(256) void scatter_perm_kernel(
    const int* __restrict__ rp, int n, int* __restrict__ cursor,
    int* __restrict__ perm) {
    __shared__ int h[64];
    __shared__ int base[64];
    if (threadIdx.x < 64) h[threadIdx.x] = 0;
    __syncthreads();
    int r = blockIdx.x * blockDim.x + threadIdx.x;
    int len = 0, rank = 0;
    if (r < n) {
        len = rp[r + 1] - rp[r]; if (len > 63) len = 63;
        rank = atomicAdd(h + len, 1);
    }
    __syncthreads();
    if (threadIdx.x < 64 && h[threadIdx.x] > 0)
        base[threadIdx.x] = atomicAdd(cursor + threadIdx.x, h[threadIdx.x]);
    __syncthreads();
    if (r < n) perm[base[len] + rank] = r;
}

// One ROW per 8-lane group (8 rows/wave), rows assigned via length-sorted
// perm so wave-max length ~= avg length (no padded gather waste).
// MODE 0: e1 = A1 @ t0 -> enew; y-stats (my,svy) -> stats; b1 -> bbuf
// MODE 1: prop = A2@eprev; en = b*prop+(1-b)*t0 -> enew; b_next -> bbuf
// MODE 2: en with y0 = emb(f32); out = (emb + e1 + e2 + eprev + en)/5
template <int MODE>
__global__ __launch_bounds__(256) void layer_kernel(
    const float* __restrict__ emb,
    const unsigned short* __restrict__ t0,
    const unsigned short* __restrict__ eprev,
    const float* __restrict__ vals, const int* __restrict__ cols,
    const int* __restrict__ rp, const int* __restrict__ perm, int n,
    unsigned short* __restrict__ enew,
    const unsigned short* __restrict__ e1t,
    const unsigned short* __restrict__ e2t,
    f2* __restrict__ stats, float* __restrict__ bbuf,
    float* __restrict__ out)
{
    const int tid  = threadIdx.x;
    const int lane = tid & 63;
    const int j    = lane & 7;
    const int wave = blockIdx.x * (blockDim.x >> 6) + (tid >> 6);
    const int vi   = wave * 8 + (lane >> 3);         // virtual (sorted) index
    const bool valid = vi < n;
    const int rg   = perm[valid ? vi : n - 1];       // actual row id

    const int start = rp[rg];
    const int end   = rp[rg + 1];
    const int len   = valid ? (end - start) : 0;
    const int b0    = start & ~1;
    const int doff  = b0 - start;

    int ml = len;
    ml = max(ml, __shfl_xor(ml, 8, 64));
    ml = max(ml, __shfl_xor(ml, 16, 64));
    ml = max(ml, __shfl_xor(ml, 32, 64));
    const int steps = (ml + 8) >> 3;

    const char* tb8 = (const char*)eprev;
    const unsigned joff = (unsigned)(j << 4);
    const size_t ro = (size_t)rg << 6;

    // early loads (hide latency under the main loop)
    float bcoef = 0.f;
    if (MODE != 0) bcoef = bbuf[rg];
    u4 yr = {};
    if (MODE != 2) yr = *((const u4*)(t0 + ro) + j);
    f2 st = {};
    if (MODE == 1) st = stats[rg];

    float acc[8] = {0.f, 0.f, 0.f, 0.f, 0.f, 0.f, 0.f, 0.f};

    for (int s = 0; s < steps; ++s) {
        const int k = b0 + (s << 3);
        u2 c01 = __builtin_nontemporal_load((const u2*)(cols + k));
        u2 c23 = __builtin_nontemporal_load((const u2*)(cols + k + 2));
        u2 c45 = __builtin_nontemporal_load((const u2*)(cols + k + 4));
        u2 c67 = __builtin_nontemporal_load((const u2*)(cols + k + 6));
        f2 v01 = __builtin_nontemporal_load((const f2*)(vals + k));
        f2 v23 = __builtin_nontemporal_load((const f2*)(vals + k + 2));
        f2 v45 = __builtin_nontemporal_load((const f2*)(vals + k + 4));
        f2 v67 = __builtin_nontemporal_load((const f2*)(vals + k + 6));
        const int rel = (s << 3) + doff;
        bool ok0 = (unsigned)(rel)     < (unsigned)len;
        bool ok1 = (unsigned)(rel + 1) < (unsigned)len;
        bool ok2 = (unsigned)(rel + 2) < (unsigned)len;
        bool ok3 = (unsigned)(rel + 3) < (unsigned)len;
        bool ok4 = (unsigned)(rel + 4) < (unsigned)len;
        bool ok5 = (unsigned)(rel + 5) < (unsigned)len;
        bool ok6 = (unsigned)(rel + 6) < (unsigned)len;
        bool ok7 = (unsigned)(rel + 7) < (unsigned)len;
        unsigned cc0 = ok0 ? (unsigned)c01.x : 0u;
        unsigned cc1 = ok1 ? (unsigned)c01.y : 0u;
        unsigned cc2 = ok2 ? (unsigned)c23.x : 0u;
        unsigned cc3 = ok3 ? (unsigned)c23.y : 0u;
        unsigned cc4 = ok4 ? (unsigned)c45.x : 0u;
        unsigned cc5 = ok5 ? (unsigned)c45.y : 0u;
        unsigned cc6 = ok6 ? (unsigned)c67.x : 0u;
        unsigned cc7 = ok7 ? (unsigned)c67.y : 0u;
        u4 g0 = *(const u4*)(tb8 + ((cc0 << 7) + joff));
        u4 g1 = *(const u4*)(tb8 + ((cc1 << 7) + joff));
        u4 g2 = *(const u4*)(tb8 + ((cc2 << 7) + joff));
        u4 g3 = *(const u4*)(tb8 + ((cc3 << 7) + joff));
        u4 g4 = *(const u4*)(tb8 + ((cc4 << 7) + joff));
        u4 g5 = *(const u4*)(tb8 + ((cc5 << 7) + joff));
        u4 g6 = *(const u4*)(tb8 + ((cc6 << 7) + joff));
        u4 g7 = *(const u4*)(tb8 + ((cc7 << 7) + joff));
        float w0 = ok0 ? v01.x : 0.f;
        float w1 = ok1 ? v01.y : 0.f;
        float w2 = ok2 ? v23.x : 0.f;
        float w3 = ok3 ? v23.y : 0.f;
        float w4 = ok4 ? v45.x : 0.f;
        float w5 = ok5 ? v45.y : 0.f;
        float w6 = ok6 ? v67.x : 0.f;
        float w7 = ok7 ? v67.y : 0.f;
        unsigned vp01 = cvtpk(w0, w1);
        unsigned vp23 = cvtpk(w2, w3);
        unsigned vp45 = cvtpk(w4, w5);
        unsigned vp67 = cvtpk(w6, w7);
#define CONSUME(ga, gb, vp)                                                    \
        acc[0] = dot2bf(__builtin_amdgcn_perm(ga.x, gb.x, SEL_LO), vp, acc[0]);\
        acc[1] = dot2bf(__builtin_amdgcn_perm(ga.x, gb.x, SEL_HI), vp, acc[1]);\
        acc[2] = dot2bf(__builtin_amdgcn_perm(ga.y, gb.y, SEL_LO), vp, acc[2]);\
        acc[3] = dot2bf(__builtin_amdgcn_perm(ga.y, gb.y, SEL_HI), vp, acc[3]);\
        acc[4] = dot2bf(__builtin_amdgcn_perm(ga.z, gb.z, SEL_LO), vp, acc[4]);\
        acc[5] = dot2bf(__builtin_amdgcn_perm(ga.z, gb.z, SEL_HI), vp, acc[5]);\
        acc[6] = dot2bf(__builtin_amdgcn_perm(ga.w, gb.w, SEL_LO), vp, acc[6]);\
        acc[7] = dot2bf(__builtin_amdgcn_perm(ga.w, gb.w, SEL_HI), vp, acc[7]);
        CONSUME(g0, g1, vp01)
        CONSUME(g2, g3, vp23)
        CONSUME(g4, g5, vp45)
        CONSUME(g6, g7, vp67)
#undef CONSUME
    }

    if (MODE == 0) {
        float sy  = dot2bf(yr.x, ONE2,
                    dot2bf(yr.y, ONE2, dot2bf(yr.z, ONE2, dot2bf(yr.w, ONE2, 0.f))));
        float syy = dot2bf(yr.x, yr.x,
                    dot2bf(yr.y, yr.y, dot2bf(yr.z, yr.z, dot2bf(yr.w, yr.w, 0.f))));
        sy = gsum8(sy); syy = gsum8(syy);
        float my  = sy * (1.f / 64.f);
        float vy  = syy - sy * my;
        float svy = sqrtf(fmaxf(vy, 0.f));
        u4 o;
        o.x = cvtpk(acc[0], acc[1]); o.y = cvtpk(acc[2], acc[3]);
        o.z = cvtpk(acc[4], acc[5]); o.w = cvtpk(acc[6], acc[7]);
        float sx  = dot2bf(o.x, ONE2,
                    dot2bf(o.y, ONE2, dot2bf(o.z, ONE2, dot2bf(o.w, ONE2, 0.f))));
        float sxx = dot2bf(o.x, o.x,
                    dot2bf(o.y, o.y, dot2bf(o.z, o.z, dot2bf(o.w, o.w, 0.f))));
        float sxy = dot2bf(o.x, yr.x,
                    dot2bf(o.y, yr.y, dot2bf(o.z, yr.z, dot2bf(o.w, yr.w, 0.f))));
        sx = gsum8(sx); sxx = gsum8(sxx); sxy = gsum8(sxy);
        float mx  = sx * (1.f / 64.f);
        float num = sxy - sx * my;
        float vx  = sxx - sx * mx;
        float den = sqrtf(fmaxf(vx, 0.f)) * svy;
        den = fmaxf(den, 1e-7f);
        float bn = num / den;
        if (valid) {
            if (j == 0) {
                f2 s2; s2.x = my; s2.y = svy;
                stats[rg] = s2;
                bbuf[rg]  = bn;
            }
            *((u4*)(enew + ro) + j) = o;
        }
        return;
    }

    const float ob = 1.f - bcoef;

    if (MODE == 1) {
        float y0[8] = { bflo(yr.x), bfhi(yr.x), bflo(yr.y), bfhi(yr.y),
                        bflo(yr.z), bfhi(yr.z), bflo(yr.w), bfhi(yr.w) };
        u4 o;
        o.x = cvtpk(bcoef * acc[0] + ob * y0[0], bcoef * acc[1] + ob * y0[1]);
        o.y = cvtpk(bcoef * acc[2] + ob * y0[2], bcoef * acc[3] + ob * y0[3]);
        o.z = cvtpk(bcoef * acc[4] + ob * y0[4], bcoef * acc[5] + ob * y0[5]);
        o.w = cvtpk(bcoef * acc[6] + ob * y0[6], bcoef * acc[7] + ob * y0[7]);
        float sx  = dot2bf(o.x, ONE2,
                    dot2bf(o.y, ONE2, dot2bf(o.z, ONE2, dot2bf(o.w, ONE2, 0.f))));
        float sxx = dot2bf(o.x, o.x,
                    dot2bf(o.y, o.y, dot2bf(o.z, o.z, dot2bf(o.w, o.w, 0.f))));
        float sxy = dot2bf(o.x, yr.x,
                    dot2bf(o.y, yr.y, dot2bf(o.z, yr.z, dot2bf(o.w, yr.w, 0.f))));
        sx = gsum8(sx); sxx = gsum8(sxx); sxy = gsum8(sxy);
        float mx  = sx * (1.f / 64.f);
        float num = sxy - sx * st.x;
        float vx  = sxx - sx * mx;
        float den = sqrtf(fmaxf(vx, 0.f)) * st.y;
        den = fmaxf(den, 1e-7f);
        float bn = num / den;
        if (valid) {
            if (j == 0) bbuf[rg] = bn;
            *((u4*)(enew + ro) + j) = o;
        }
    } else {
        const f4* ep = (const f4*)(emb + ro) + 2 * j;
        f4 ea = ep[0], eb = ep[1];
        float y0[8] = { ea.x, ea.y, ea.z, ea.w, eb.x, eb.y, eb.z, eb.w };
        u4 xr = *((const u4*)(eprev + ro) + j);
        float xp[8] = { bflo(xr.x), bfhi(xr.x), bflo(xr.y), bfhi(xr.y),
                        bflo(xr.z), bfhi(xr.z), bflo(xr.w), bfhi(xr.w) };
        u4 r1 = *((const u4*)(e1t + ro) + j);
        u4 r2 = *((const u4*)(e2t + ro) + j);
        float s[8];
        s[0] = y0[0] + bflo(r1.x) + bflo(r2.x) + xp[0] + (bcoef * acc[0] + ob * y0[0]);
        s[1] = y0[1] + bfhi(r1.x) + bfhi(r2.x) + xp[1] + (bcoef * acc[1] + ob * y0[1]);
        s[2] = y0[2] + bflo(r1.y) + bflo(r2.y) + xp[2] + (bcoef * acc[2] + ob * y0[2]);
        s[3] = y0[3] + bfhi(r1.y) + bfhi(r2.y) + xp[3] + (bcoef * acc[3] + ob * y0[3]);
        s[4] = y0[4] + bflo(r1.z) + bflo(r2.z) + xp[4] + (bcoef * acc[4] + ob * y0[4]);
        s[5] = y0[5] + bfhi(r1.z) + bfhi(r2.z) + xp[5] + (bcoef * acc[5] + ob * y0[5]);
        s[6] = y0[6] + bflo(r1.w) + bflo(r2.w) + xp[6] + (bcoef * acc[6] + ob * y0[6]);
        s[7] = y0[7] + bfhi(r1.w) + bfhi(r2.w) + xp[7] + (bcoef * acc[7] + ob * y0[7]);
        if (valid) {
            f4 o0 = { s[0] * 0.2f, s[1] * 0.2f, s[2] * 0.2f, s[3] * 0.2f };
            f4 o1 = { s[4] * 0.2f, s[5] * 0.2f, s[6] * 0.2f, s[7] * 0.2f };
            f4* op = (f4*)(out + ro) + 2 * j;
            op[0] = o0; op[1] = o1;
        }
    }
}

extern "C" void kernel_launch(void* const* d_in, const int* in_sizes, int n_in,
                              void* d_out, int out_size, void* d_ws, size_t ws_size,
                              hipStream_t stream) {
    const float* emb   = (const float*)d_in[0];
    const float* vals  = (const float*)d_in[1];
    const float* vals2 = (const float*)d_in[2];
    const int*   rows  = (const int*)d_in[3];
    const int*   cols  = (const int*)d_in[4];
    const int*   rows2 = (const int*)d_in[5];
    const int*   cols2 = (const int*)d_in[6];
    // n_layers = 3 (fixed for this problem)

    const int n    = in_sizes[0] / DIM;   // 300000
    const int nnz  = in_sizes[1];         // 4800000
    const int nnz2 = in_sizes[2];

    float* out = (float*)d_out;

    // ws: rp1 | rp2 | ST | BB | P1 | P2 | HIST(h1,h2,c1,c2) | T0 | E1 | E2 | E3
    char*  ws       = (char*)d_ws;
    size_t rp_bytes = (((size_t)(n + 1) * sizeof(int)) + 255) & ~(size_t)255;
    size_t st_bytes = (((size_t)n * sizeof(f2)) + 255) & ~(size_t)255;
    size_t bb_bytes = (((size_t)n * sizeof(float)) + 255) & ~(size_t)255;
    size_t pm_bytes = (((size_t)n * sizeof(int)) + 255) & ~(size_t)255;
    size_t tb_bytes = (size_t)n * DIM * sizeof(unsigned short);
    int*   rp1 = (int*)ws;
    int*   rp2 = (int*)(ws + rp_bytes);
    f2*    ST  = (f2*)(ws + 2 * rp_bytes);
    float* BB  = (float*)(ws + 2 * rp_bytes + st_bytes);
    int*   P1  = (int*)(ws + 2 * rp_bytes + st_bytes + bb_bytes);
    int*   P2  = (int*)((char*)P1 + pm_bytes);
    int*   HIST = (int*)((char*)P2 + pm_bytes);        // h1[64] h2[64] c1[64] c2[64]
    int*   H1 = HIST, *H2 = HIST + 64, *C1 = HIST + 128, *C2 = HIST + 192;
    unsigned short* T0 = (unsigned short*)((char*)HIST + 1024);
    unsigned short* E1 = (unsigned short*)((char*)T0 + tb_bytes);
    unsigned short* E2 = (unsigned short*)((char*)E1 + tb_bytes);
    unsigned short* E3 = (unsigned short*)((char*)E2 + tb_bytes);

    const int tb = 256;
    const int nblk = (n + tb - 1) / tb;
    build_row_ptr_kernel<<<(n + 1 + tb - 1) / tb, tb, 0, stream>>>(rows,  nnz,  n, rp1);
    build_row_ptr_kernel<<<(n + 1 + tb - 1) / tb, tb, 0, stream>>>(rows2, nnz2, n, rp2);

    const int n8 = n * DIM / 8;
    cvt_bf16_kernel<<<(n8 + tb - 1) / tb, tb, 0, stream>>>(emb, (unsigned int*)T0, n8);

    // block-aggregated length counting-sort -> P1 (rp1), P2 (rp2)
    zero_hist_kernel<<<1, 128, 0, stream>>>(HIST);     // h1,h2
    hist_kernel<<<nblk, tb, 0, stream>>>(rp1, n, H1);
    hist_kernel<<<nblk, tb, 0, stream>>>(rp2, n, H2);
    scan_hist_kernel<<<1, 64, 0, stream>>>(H1, C1);
    scan_hist_kernel<<<1, 64, 0, stream>>>(H2, C2);
    scatter_perm_kernel<<<nblk, tb, 0, stream>>>(rp1, n, C1, P1);
    scatter_perm_kernel<<<nblk, tb, 0, stream>>>(rp2, n, C2, P2);

    const int waves = (n + 7) / 8;            // 8 rows per wave
    const int grid  = (waves + 3) / 4;        // 4 waves per 256-thread block
    layer_kernel<0><<<grid, tb, 0, stream>>>(emb, T0, T0, vals, cols, rp1, P1, n,
                                             E1, T0, T0, ST, BB, out);
    layer_kernel<1><<<grid, tb, 0, stream>>>(emb, T0, E1, vals2, cols2, rp2, P2, n,
                                             E2, T0, T0, ST, BB, out);
    layer_kernel<1><<<grid, tb, 0, stream>>>(emb, T0, E2, vals2, cols2, rp2, P2, n,
                                             E3, T0, T0, ST, BB, out);
    layer_kernel<2><<<grid, tb, 0, stream>>>(emb, T0, E3, vals2, cols2, rp2, P2, n,
                                             E3, E1, E2, ST, BB, out);
}

// Round 10
// 503.945 us; speedup vs baseline: 7.4674x; 1.3329x over previous
//
#include <hip/hip_runtime.h>

#define DIM 64

typedef __attribute__((ext_vector_type(4))) float f4;
typedef __attribute__((ext_vector_type(2))) float f2;
typedef __attribute__((ext_vector_type(4))) unsigned int u4;
typedef __attribute__((ext_vector_type(2))) unsigned int u2;

#define SEL_LO 0x01000504u   // [src0.lo16 | src1.lo16<<16]
#define SEL_HI 0x03020706u   // [src0.hi16 | src1.hi16<<16]
#define ONE2   0x3f803f80u   // bf16 pair (1.0, 1.0)

// ---- bf16 helpers ----
__device__ __forceinline__ float bflo(unsigned u) { return __uint_as_float(u << 16); }
__device__ __forceinline__ float bfhi(unsigned u) { return __uint_as_float(u & 0xffff0000u); }
__device__ __forceinline__ unsigned bfr(float f) {
    unsigned u = __float_as_uint(f);
    return (u + 0x7fffu + ((u >> 16) & 1u)) >> 16;
}
__device__ __forceinline__ unsigned packbf(float e, float o) { return bfr(e) | (bfr(o) << 16); }
__device__ __forceinline__ unsigned cvtpk(float lo, float hi) {
    unsigned r;
    asm("v_cvt_pk_bf16_f32 %0, %1, %2" : "=v"(r) : "v"(lo), "v"(hi));
    return r;
}
__device__ __forceinline__ float dot2bf(unsigned a, unsigned b, float c) {
    float d;
    asm("v_dot2_f32_bf16 %0, %1, %2, %3" : "=v"(d) : "v"(a), "v"(b), "v"(c));
    return d;
}
__device__ __forceinline__ float gsum8(float v) {
    v += __shfl_xor(v, 1, 64);
    v += __shfl_xor(v, 2, 64);
    v += __shfl_xor(v, 4, 64);
    return v;
}

// Fused: rpA[r] = lower_bound(rowsA, r), rpB[r] = lower_bound(rowsB, r).
__global__ void build_row_ptr2_kernel(const int* __restrict__ rowsA, int nnzA,
                                      const int* __restrict__ rowsB, int nnzB,
                                      int n, int* __restrict__ rpA,
                                      int* __restrict__ rpB) {
    int i = blockIdx.x * blockDim.x + threadIdx.x;
    const int* rows; int nnz; int* rp; int r;
    if (i <= n) { rows = rowsA; nnz = nnzA; rp = rpA; r = i; }
    else {
        r = i - (n + 1);
        if (r > n) return;
        rows = rowsB; nnz = nnzB; rp = rpB;
    }
    int lo = 0, hi = nnz;
    while (lo < hi) {
        int mid = (lo + hi) >> 1;
        if (rows[mid] < r) lo = mid + 1; else hi = mid;
    }
    rp[r] = lo;
}

// f32 -> packed bf16 table, 8 elems per thread.
__global__ void cvt_bf16_kernel(const float* __restrict__ in,
                                unsigned int* __restrict__ out, int n8) {
    int i = blockIdx.x * blockDim.x + threadIdx.x;
    if (i >= n8) return;
    const f4* p = (const f4*)in + 2 * (size_t)i;
    f4 a = p[0], b = p[1];
    u4 o;
    o.x = packbf(a.x, a.y); o.y = packbf(a.z, a.w);
    o.z = packbf(b.x, b.y); o.w = packbf(b.z, b.w);
    ((u4*)out)[i] = o;
}

// One ROW per 8-lane group (8 rows/wave); lane j owns dims 8j..8j+7.
// 8 nnz per step, 8 independent dwordx4 gathers in flight.
// MODE 0: e1 = A1 @ t0 -> enew; y-stats (my,svy) -> stats; b1 -> bbuf
// MODE 1: prop = A2@eprev; en = b*prop+(1-b)*t0 -> enew; b_next -> bbuf
// MODE 2: as MODE1; out = (t0 + e1 + e2 + eprev + en)/5  (f32)
template <int MODE>
__global__ __launch_bounds__(256) void layer_kernel(
    const unsigned short* __restrict__ t0,
    const unsigned short* __restrict__ eprev,
    const float* __restrict__ vals, const int* __restrict__ cols,
    const int* __restrict__ rp, int n,
    unsigned short* __restrict__ enew,
    const unsigned short* __restrict__ e1t,
    const unsigned short* __restrict__ e2t,
    f2* __restrict__ stats, float* __restrict__ bbuf,
    float* __restrict__ out)
{
    const int tid  = threadIdx.x;
    const int lane = tid & 63;
    const int j    = lane & 7;
    const int wave = blockIdx.x * (blockDim.x >> 6) + (tid >> 6);
    const int rowg = wave * 8 + (lane >> 3);
    const bool valid = rowg < n;
    const int rg   = valid ? rowg : n - 1;

    const int start = rp[rg];
    const int end   = rp[rg + 1];
    const int len   = valid ? (end - start) : 0;
    const int b0    = start & ~1;
    const int doff  = b0 - start;

    int ml = len;
    ml = max(ml, __shfl_xor(ml, 8, 64));
    ml = max(ml, __shfl_xor(ml, 16, 64));
    ml = max(ml, __shfl_xor(ml, 32, 64));
    const int steps = (ml + 8) >> 3;

    const char* tb8 = (const char*)eprev;
    const unsigned joff = (unsigned)(j << 4);
    const size_t ro = (size_t)rg << 6;

    // early loads (hide latency under the main loop)
    float bcoef = 0.f;
    if (MODE != 0) bcoef = bbuf[rg];
    u4 yr = *((const u4*)(t0 + ro) + j);
    f2 st = {};
    if (MODE == 1) st = stats[rg];

    float acc[8] = {0.f, 0.f, 0.f, 0.f, 0.f, 0.f, 0.f, 0.f};

    for (int s = 0; s < steps; ++s) {
        const int k = b0 + (s << 3);
        u2 c01 = __builtin_nontemporal_load((const u2*)(cols + k));
        u2 c23 = __builtin_nontemporal_load((const u2*)(cols + k + 2));
        u2 c45 = __builtin_nontemporal_load((const u2*)(cols + k + 4));
        u2 c67 = __builtin_nontemporal_load((const u2*)(cols + k + 6));
        f2 v01 = __builtin_nontemporal_load((const f2*)(vals + k));
        f2 v23 = __builtin_nontemporal_load((const f2*)(vals + k + 2));
        f2 v45 = __builtin_nontemporal_load((const f2*)(vals + k + 4));
        f2 v67 = __builtin_nontemporal_load((const f2*)(vals + k + 6));
        const int rel = (s << 3) + doff;
        bool ok0 = (unsigned)(rel)     < (unsigned)len;
        bool ok1 = (unsigned)(rel + 1) < (unsigned)len;
        bool ok2 = (unsigned)(rel + 2) < (unsigned)len;
        bool ok3 = (unsigned)(rel + 3) < (unsigned)len;
        bool ok4 = (unsigned)(rel + 4) < (unsigned)len;
        bool ok5 = (unsigned)(rel + 5) < (unsigned)len;
        bool ok6 = (unsigned)(rel + 6) < (unsigned)len;
        bool ok7 = (unsigned)(rel + 7) < (unsigned)len;
        unsigned cc0 = ok0 ? (unsigned)c01.x : 0u;
        unsigned cc1 = ok1 ? (unsigned)c01.y : 0u;
        unsigned cc2 = ok2 ? (unsigned)c23.x : 0u;
        unsigned cc3 = ok3 ? (unsigned)c23.y : 0u;
        unsigned cc4 = ok4 ? (unsigned)c45.x : 0u;
        unsigned cc5 = ok5 ? (unsigned)c45.y : 0u;
        unsigned cc6 = ok6 ? (unsigned)c67.x : 0u;
        unsigned cc7 = ok7 ? (unsigned)c67.y : 0u;
        u4 g0 = *(const u4*)(tb8 + ((cc0 << 7) + joff));
        u4 g1 = *(const u4*)(tb8 + ((cc1 << 7) + joff));
        u4 g2 = *(const u4*)(tb8 + ((cc2 << 7) + joff));
        u4 g3 = *(const u4*)(tb8 + ((cc3 << 7) + joff));
        u4 g4 = *(const u4*)(tb8 + ((cc4 << 7) + joff));
        u4 g5 = *(const u4*)(tb8 + ((cc5 << 7) + joff));
        u4 g6 = *(const u4*)(tb8 + ((cc6 << 7) + joff));
        u4 g7 = *(const u4*)(tb8 + ((cc7 << 7) + joff));
        float w0 = ok0 ? v01.x : 0.f;
        float w1 = ok1 ? v01.y : 0.f;
        float w2 = ok2 ? v23.x : 0.f;
        float w3 = ok3 ? v23.y : 0.f;
        float w4 = ok4 ? v45.x : 0.f;
        float w5 = ok5 ? v45.y : 0.f;
        float w6 = ok6 ? v67.x : 0.f;
        float w7 = ok7 ? v67.y : 0.f;
        unsigned vp01 = cvtpk(w0, w1);
        unsigned vp23 = cvtpk(w2, w3);
        unsigned vp45 = cvtpk(w4, w5);
        unsigned vp67 = cvtpk(w6, w7);
#define CONSUME(ga, gb, vp)                                                    \
        acc[0] = dot2bf(__builtin_amdgcn_perm(ga.x, gb.x, SEL_LO), vp, acc[0]);\
        acc[1] = dot2bf(__builtin_amdgcn_perm(ga.x, gb.x, SEL_HI), vp, acc[1]);\
        acc[2] = dot2bf(__builtin_amdgcn_perm(ga.y, gb.y, SEL_LO), vp, acc[2]);\
        acc[3] = dot2bf(__builtin_amdgcn_perm(ga.y, gb.y, SEL_HI), vp, acc[3]);\
        acc[4] = dot2bf(__builtin_amdgcn_perm(ga.z, gb.z, SEL_LO), vp, acc[4]);\
        acc[5] = dot2bf(__builtin_amdgcn_perm(ga.z, gb.z, SEL_HI), vp, acc[5]);\
        acc[6] = dot2bf(__builtin_amdgcn_perm(ga.w, gb.w, SEL_LO), vp, acc[6]);\
        acc[7] = dot2bf(__builtin_amdgcn_perm(ga.w, gb.w, SEL_HI), vp, acc[7]);
        CONSUME(g0, g1, vp01)
        CONSUME(g2, g3, vp23)
        CONSUME(g4, g5, vp45)
        CONSUME(g6, g7, vp67)
#undef CONSUME
    }

    if (MODE == 0) {
        float sy  = dot2bf(yr.x, ONE2,
                    dot2bf(yr.y, ONE2, dot2bf(yr.z, ONE2, dot2bf(yr.w, ONE2, 0.f))));
        float syy = dot2bf(yr.x, yr.x,
                    dot2bf(yr.y, yr.y, dot2bf(yr.z, yr.z, dot2bf(yr.w, yr.w, 0.f))));
        sy = gsum8(sy); syy = gsum8(syy);
        float my  = sy * (1.f / 64.f);
        float vy  = syy - sy * my;
        float svy = sqrtf(fmaxf(vy, 0.f));
        u4 o;
        o.x = cvtpk(acc[0], acc[1]); o.y = cvtpk(acc[2], acc[3]);
        o.z = cvtpk(acc[4], acc[5]); o.w = cvtpk(acc[6], acc[7]);
        float sx  = dot2bf(o.x, ONE2,
                    dot2bf(o.y, ONE2, dot2bf(o.z, ONE2, dot2bf(o.w, ONE2, 0.f))));
        float sxx = dot2bf(o.x, o.x,
                    dot2bf(o.y, o.y, dot2bf(o.z, o.z, dot2bf(o.w, o.w, 0.f))));
        float sxy = dot2bf(o.x, yr.x,
                    dot2bf(o.y, yr.y, dot2bf(o.z, yr.z, dot2bf(o.w, yr.w, 0.f))));
        sx = gsum8(sx); sxx = gsum8(sxx); sxy = gsum8(sxy);
        float mx  = sx * (1.f / 64.f);
        float num = sxy - sx * my;
        float vx  = sxx - sx * mx;
        float den = sqrtf(fmaxf(vx, 0.f)) * svy;
        den = fmaxf(den, 1e-7f);
        float bn = num / den;
        if (valid) {
            if (j == 0) {
                f2 s2; s2.x = my; s2.y = svy;
                __builtin_nontemporal_store(s2, stats + rg);
                __builtin_nontemporal_store(bn, bbuf + rg);
            }
            __builtin_nontemporal_store(o, (u4*)(enew + ro) + j);
        }
        return;
    }

    const float ob = 1.f - bcoef;

    if (MODE == 1) {
        float y0[8] = { bflo(yr.x), bfhi(yr.x), bflo(yr.y), bfhi(yr.y),
                        bflo(yr.z), bfhi(yr.z), bflo(yr.w), bfhi(yr.w) };
        u4 o;
        o.x = cvtpk(bcoef * acc[0] + ob * y0[0], bcoef * acc[1] + ob * y0[1]);
        o.y = cvtpk(bcoef * acc[2] + ob * y0[2], bcoef * acc[3] + ob * y0[3]);
        o.z = cvtpk(bcoef * acc[4] + ob * y0[4], bcoef * acc[5] + ob * y0[5]);
        o.w = cvtpk(bcoef * acc[6] + ob * y0[6], bcoef * acc[7] + ob * y0[7]);
        float sx  = dot2bf(o.x, ONE2,
                    dot2bf(o.y, ONE2, dot2bf(o.z, ONE2, dot2bf(o.w, ONE2, 0.f))));
        float sxx = dot2bf(o.x, o.x,
                    dot2bf(o.y, o.y, dot2bf(o.z, o.z, dot2bf(o.w, o.w, 0.f))));
        float sxy = dot2bf(o.x, yr.x,
                    dot2bf(o.y, yr.y, dot2bf(o.z, yr.z, dot2bf(o.w, yr.w, 0.f))));
        sx = gsum8(sx); sxx = gsum8(sxx); sxy = gsum8(sxy);
        float mx  = sx * (1.f / 64.f);
        float num = sxy - sx * st.x;
        float vx  = sxx - sx * mx;
        float den = sqrtf(fmaxf(vx, 0.f)) * st.y;
        den = fmaxf(den, 1e-7f);
        float bn = num / den;
        if (valid) {
            if (j == 0) __builtin_nontemporal_store(bn, bbuf + rg);
            __builtin_nontemporal_store(o, (u4*)(enew + ro) + j);
        }
    } else {
        // MODE 2: y0 from t0 (bf16); fused mean -> out (f32)
        float y0[8] = { bflo(yr.x), bfhi(yr.x), bflo(yr.y), bfhi(yr.y),
                        bflo(yr.z), bfhi(yr.z), bflo(yr.w), bfhi(yr.w) };
        u4 xr = *((const u4*)(eprev + ro) + j);
        float xp[8] = { bflo(xr.x), bfhi(xr.x), bflo(xr.y), bfhi(xr.y),
                        bflo(xr.z), bfhi(xr.z), bflo(xr.w), bfhi(xr.w) };
        u4 r1 = *((const u4*)(e1t + ro) + j);
        u4 r2 = *((const u4*)(e2t + ro) + j);
        float s[8];
        s[0] = y0[0] + bflo(r1.x) + bflo(r2.x) + xp[0] + (bcoef * acc[0] + ob * y0[0]);
        s[1] = y0[1] + bfhi(r1.x) + bfhi(r2.x) + xp[1] + (bcoef * acc[1] + ob * y0[1]);
        s[2] = y0[2] + bflo(r1.y) + bflo(r2.y) + xp[2] + (bcoef * acc[2] + ob * y0[2]);
        s[3] = y0[3] + bfhi(r1.y) + bfhi(r2.y) + xp[3] + (bcoef * acc[3] + ob * y0[3]);
        s[4] = y0[4] + bflo(r1.z) + bflo(r2.z) + xp[4] + (bcoef * acc[4] + ob * y0[4]);
        s[5] = y0[5] + bfhi(r1.z) + bfhi(r2.z) + xp[5] + (bcoef * acc[5] + ob * y0[5]);
        s[6] = y0[6] + bflo(r1.w) + bflo(r2.w) + xp[6] + (bcoef * acc[6] + ob * y0[6]);
        s[7] = y0[7] + bfhi(r1.w) + bfhi(r2.w) + xp[7] + (bcoef * acc[7] + ob * y0[7]);
        if (valid) {
            f4 o0 = { s[0] * 0.2f, s[1] * 0.2f, s[2] * 0.2f, s[3] * 0.2f };
            f4 o1 = { s[4] * 0.2f, s[5] * 0.2f, s[6] * 0.2f, s[7] * 0.2f };
            f4* op = (f4*)(out + ro) + 2 * j;
            __builtin_nontemporal_store(o0, op);
            __builtin_nontemporal_store(o1, op + 1);
        }
    }
}

extern "C" void kernel_launch(void* const* d_in, const int* in_sizes, int n_in,
                              void* d_out, int out_size, void* d_ws, size_t ws_size,
                              hipStream_t stream) {
    const float* emb   = (const float*)d_in[0];
    const float* vals  = (const float*)d_in[1];
    const float* vals2 = (const float*)d_in[2];
    const int*   rows  = (const int*)d_in[3];
    const int*   cols  = (const int*)d_in[4];
    const int*   rows2 = (const int*)d_in[5];
    const int*   cols2 = (const int*)d_in[6];
    // n_layers = 3 (fixed for this problem)

    const int n    = in_sizes[0] / DIM;   // 300000
    const int nnz  = in_sizes[1];         // 4800000
    const int nnz2 = in_sizes[2];

    float* out = (float*)d_out;

    // ws: rp1 | rp2 | ST | BB | T0 | E1 | E2 | E3  (~160 MB)
    char*  ws       = (char*)d_ws;
    size_t rp_bytes = (((size_t)(n + 1) * sizeof(int)) + 255) & ~(size_t)255;
    size_t st_bytes = (((size_t)n * sizeof(f2)) + 255) & ~(size_t)255;
    size_t bb_bytes = (((size_t)n * sizeof(float)) + 255) & ~(size_t)255;
    size_t tb_bytes = (size_t)n * DIM * sizeof(unsigned short);
    int*   rp1 = (int*)ws;
    int*   rp2 = (int*)(ws + rp_bytes);
    f2*    ST  = (f2*)(ws + 2 * rp_bytes);
    float* BB  = (float*)(ws + 2 * rp_bytes + st_bytes);
    unsigned short* T0 = (unsigned short*)(ws + 2 * rp_bytes + st_bytes + bb_bytes);
    unsigned short* E1 = (unsigned short*)((char*)T0 + tb_bytes);
    unsigned short* E2 = (unsigned short*)((char*)E1 + tb_bytes);
    unsigned short* E3 = (unsigned short*)((char*)E2 + tb_bytes);

    const int tb = 256;
    build_row_ptr2_kernel<<<(2 * (n + 1) + tb - 1) / tb, tb, 0, stream>>>(
        rows, nnz, rows2, nnz2, n, rp1, rp2);

    const int n8 = n * DIM / 8;
    cvt_bf16_kernel<<<(n8 + tb - 1) / tb, tb, 0, stream>>>(emb, (unsigned int*)T0, n8);

    const int waves = (n + 7) / 8;            // 8 rows per wave
    const int grid  = (waves + 3) / 4;        // 4 waves per 256-thread block
    // e1 = A1 @ t0 ; y-stats ; b1
    layer_kernel<0><<<grid, tb, 0, stream>>>(T0, T0, vals, cols, rp1, n,
                                             E1, T0, T0, ST, BB, out);
    // e2 from e1 ; b2
    layer_kernel<1><<<grid, tb, 0, stream>>>(T0, E1, vals2, cols2, rp2, n,
                                             E2, T0, T0, ST, BB, out);
    // e3 from e2 ; b3
    layer_kernel<1><<<grid, tb, 0, stream>>>(T0, E2, vals2, cols2, rp2, n,
                                             E3, T0, T0, ST, BB, out);
    // final: e4 from e3, fused mean -> out
    layer_kernel<2><<<grid, tb, 0, stream>>>(T0, E3, vals2, cols2, rp2, n,
                                             E3, E1, E2, ST, BB, out);
}

// Round 11
// 474.382 us; speedup vs baseline: 7.9328x; 1.0623x over previous
//
#include <hip/hip_runtime.h>

#define DIM 64
#define SC  32.0f      // fp8 table scale (clears e4m3 subnormal band)
#define ISC 0.03125f   // 1/SC

typedef __attribute__((ext_vector_type(4))) float f4;
typedef __attribute__((ext_vector_type(2))) float f2;
typedef __attribute__((ext_vector_type(4))) unsigned int u4;
typedef __attribute__((ext_vector_type(2))) unsigned int u2;

#define ONE2 0x3f803f80u   // bf16 pair (1.0, 1.0)

// ---- bf16 helpers ----
__device__ __forceinline__ float bflo(unsigned u) { return __uint_as_float(u << 16); }
__device__ __forceinline__ float bfhi(unsigned u) { return __uint_as_float(u & 0xffff0000u); }
__device__ __forceinline__ unsigned bfr(float f) {
    unsigned u = __float_as_uint(f);
    return (u + 0x7fffu + ((u >> 16) & 1u)) >> 16;
}
__device__ __forceinline__ unsigned packbf(float e, float o) { return bfr(e) | (bfr(o) << 16); }
__device__ __forceinline__ unsigned cvtpk(float lo, float hi) {
    unsigned r;
    asm("v_cvt_pk_bf16_f32 %0, %1, %2" : "=v"(r) : "v"(lo), "v"(hi));
    return r;
}
__device__ __forceinline__ float dot2bf(unsigned a, unsigned b, float c) {
    float d;
    asm("v_dot2_f32_bf16 %0, %1, %2, %3" : "=v"(d) : "v"(a), "v"(b), "v"(c));
    return d;
}
__device__ __forceinline__ float gsum8(float v) {
    v += __shfl_xor(v, 1, 64);
    v += __shfl_xor(v, 2, 64);
    v += __shfl_xor(v, 4, 64);
    return v;
}

// Fused: rpA[r] = lower_bound(rowsA, r), rpB[r] = lower_bound(rowsB, r).
__global__ void build_row_ptr2_kernel(const int* __restrict__ rowsA, int nnzA,
                                      const int* __restrict__ rowsB, int nnzB,
                                      int n, int* __restrict__ rpA,
                                      int* __restrict__ rpB) {
    int i = blockIdx.x * blockDim.x + threadIdx.x;
    const int* rows; int nnz; int* rp; int r;
    if (i <= n) { rows = rowsA; nnz = nnzA; rp = rpA; r = i; }
    else {
        r = i - (n + 1);
        if (r > n) return;
        rows = rowsB; nnz = nnzB; rp = rpB;
    }
    int lo = 0, hi = nnz;
    while (lo < hi) {
        int mid = (lo + hi) >> 1;
        if (rows[mid] < r) lo = mid + 1; else hi = mid;
    }
    rp[r] = lo;
}

// f32 -> bf16 table + fp8(x*SC) table, 8 elems per thread.
__global__ void cvt_kernel(const float* __restrict__ in,
                           unsigned int* __restrict__ obf,
                           unsigned char* __restrict__ of8, int n8) {
    int i = blockIdx.x * blockDim.x + threadIdx.x;
    if (i >= n8) return;
    const f4* p = (const f4*)in + 2 * (size_t)i;
    f4 a = p[0], b = p[1];
    u4 o;
    o.x = packbf(a.x, a.y); o.y = packbf(a.z, a.w);
    o.z = packbf(b.x, b.y); o.w = packbf(b.z, b.w);
    ((u4*)obf)[i] = o;
    int lo = 0, hi = 0;
    lo = __builtin_amdgcn_cvt_pk_fp8_f32(a.x * SC, a.y * SC, lo, false);
    lo = __builtin_amdgcn_cvt_pk_fp8_f32(a.z * SC, a.w * SC, lo, true);
    hi = __builtin_amdgcn_cvt_pk_fp8_f32(b.x * SC, b.y * SC, hi, false);
    hi = __builtin_amdgcn_cvt_pk_fp8_f32(b.z * SC, b.w * SC, hi, true);
    u2 w8; w8.x = (unsigned)lo; w8.y = (unsigned)hi;
    ((u2*)of8)[i] = w8;
}

// One ROW per 8-lane group (8 rows/wave); lane j owns dims 8j..8j+7.
// Gathers read the fp8 (x*32) table: 64B rows, dwordx2 per lane.
// MODE 0: e1 = A1 @ T0f8 -> bfout(E1) + f8out; y-stats; b1 -> bbuf
// MODE 1: prop = A2@gtab; en = b*prop+(1-b)*t0; b_next -> bbuf; f8out = fp8(en)
//         SUM ? bfout = e1row + en (S12) : bfout = bf16(en) (E3)
// MODE 2: en as MODE1; out = (t0 + s12 + e3 + en)/5  (f32)
template <int MODE, bool SUM>
__global__ __launch_bounds__(256) void layer_kernel(
    const unsigned short* __restrict__ t0,
    const unsigned char*  __restrict__ gtab,
    const float* __restrict__ vals, const int* __restrict__ cols,
    const int* __restrict__ rp, int n,
    unsigned short* __restrict__ bfout,
    unsigned char*  __restrict__ f8out,
    const unsigned short* __restrict__ e1in,
    const unsigned short* __restrict__ e3in,
    const unsigned short* __restrict__ s12in,
    f2* __restrict__ stats, float* __restrict__ bbuf,
    float* __restrict__ out)
{
    const int tid  = threadIdx.x;
    const int lane = tid & 63;
    const int j    = lane & 7;
    const int wave = blockIdx.x * (blockDim.x >> 6) + (tid >> 6);
    const int rowg = wave * 8 + (lane >> 3);
    const bool valid = rowg < n;
    const int rg   = valid ? rowg : n - 1;

    const int start = rp[rg];
    const int end   = rp[rg + 1];
    const int len   = valid ? (end - start) : 0;
    const int b0    = start & ~1;
    const int doff  = b0 - start;

    int ml = len;
    ml = max(ml, __shfl_xor(ml, 8, 64));
    ml = max(ml, __shfl_xor(ml, 16, 64));
    ml = max(ml, __shfl_xor(ml, 32, 64));
    const int steps = (ml + 8) >> 3;

    const unsigned joff8 = (unsigned)(j << 3);
    const size_t ro = (size_t)rg << 6;

    // early row-stream loads (hide under main loop); all single-use -> nt
    float bcoef = 0.f;
    if (MODE != 0) bcoef = __builtin_nontemporal_load(bbuf + rg);
    u4 yr = __builtin_nontemporal_load((const u4*)(t0 + ro) + j);
    f2 st = {};
    if (MODE == 1) st = __builtin_nontemporal_load(stats + rg);

    f2 a01 = {0.f, 0.f}, a23 = {0.f, 0.f}, a45 = {0.f, 0.f}, a67 = {0.f, 0.f};

    for (int s = 0; s < steps; ++s) {
        const int k = b0 + (s << 3);
        u2 c01 = __builtin_nontemporal_load((const u2*)(cols + k));
        u2 c23 = __builtin_nontemporal_load((const u2*)(cols + k + 2));
        u2 c45 = __builtin_nontemporal_load((const u2*)(cols + k + 4));
        u2 c67 = __builtin_nontemporal_load((const u2*)(cols + k + 6));
        f2 v01 = __builtin_nontemporal_load((const f2*)(vals + k));
        f2 v23 = __builtin_nontemporal_load((const f2*)(vals + k + 2));
        f2 v45 = __builtin_nontemporal_load((const f2*)(vals + k + 4));
        f2 v67 = __builtin_nontemporal_load((const f2*)(vals + k + 6));
        const int rel = (s << 3) + doff;
        bool ok0 = (unsigned)(rel)     < (unsigned)len;
        bool ok1 = (unsigned)(rel + 1) < (unsigned)len;
        bool ok2 = (unsigned)(rel + 2) < (unsigned)len;
        bool ok3 = (unsigned)(rel + 3) < (unsigned)len;
        bool ok4 = (unsigned)(rel + 4) < (unsigned)len;
        bool ok5 = (unsigned)(rel + 5) < (unsigned)len;
        bool ok6 = (unsigned)(rel + 6) < (unsigned)len;
        bool ok7 = (unsigned)(rel + 7) < (unsigned)len;
        unsigned cc0 = ok0 ? (unsigned)c01.x : 0u;
        unsigned cc1 = ok1 ? (unsigned)c01.y : 0u;
        unsigned cc2 = ok2 ? (unsigned)c23.x : 0u;
        unsigned cc3 = ok3 ? (unsigned)c23.y : 0u;
        unsigned cc4 = ok4 ? (unsigned)c45.x : 0u;
        unsigned cc5 = ok5 ? (unsigned)c45.y : 0u;
        unsigned cc6 = ok6 ? (unsigned)c67.x : 0u;
        unsigned cc7 = ok7 ? (unsigned)c67.y : 0u;
        // 8 independent 8B gathers in flight
        u2 g0 = *(const u2*)(gtab + ((cc0 << 6) + joff8));
        u2 g1 = *(const u2*)(gtab + ((cc1 << 6) + joff8));
        u2 g2 = *(const u2*)(gtab + ((cc2 << 6) + joff8));
        u2 g3 = *(const u2*)(gtab + ((cc3 << 6) + joff8));
        u2 g4 = *(const u2*)(gtab + ((cc4 << 6) + joff8));
        u2 g5 = *(const u2*)(gtab + ((cc5 << 6) + joff8));
        u2 g6 = *(const u2*)(gtab + ((cc6 << 6) + joff8));
        u2 g7 = *(const u2*)(gtab + ((cc7 << 6) + joff8));
        float w0 = ok0 ? v01.x : 0.f;
        float w1 = ok1 ? v01.y : 0.f;
        float w2 = ok2 ? v23.x : 0.f;
        float w3 = ok3 ? v23.y : 0.f;
        float w4 = ok4 ? v45.x : 0.f;
        float w5 = ok5 ? v45.y : 0.f;
        float w6 = ok6 ? v67.x : 0.f;
        float w7 = ok7 ? v67.y : 0.f;
#define CONS(gg, ww) {                                                        \
        f2 wv; wv.x = (ww); wv.y = (ww);                                      \
        f2 p0 = __builtin_amdgcn_cvt_pk_f32_fp8((int)gg.x, false);            \
        f2 p1 = __builtin_amdgcn_cvt_pk_f32_fp8((int)gg.x, true);             \
        f2 p2 = __builtin_amdgcn_cvt_pk_f32_fp8((int)gg.y, false);            \
        f2 p3 = __builtin_amdgcn_cvt_pk_f32_fp8((int)gg.y, true);             \
        a01 += wv * p0; a23 += wv * p1; a45 += wv * p2; a67 += wv * p3;       \
    }
        CONS(g0, w0) CONS(g1, w1) CONS(g2, w2) CONS(g3, w3)
        CONS(g4, w4) CONS(g5, w5) CONS(g6, w6) CONS(g7, w7)
#undef CONS
    }

    float acc[8] = { a01.x * ISC, a01.y * ISC, a23.x * ISC, a23.y * ISC,
                     a45.x * ISC, a45.y * ISC, a67.x * ISC, a67.y * ISC };

    if (MODE == 0) {
        // y-stats of t0 row (loop-invariant across layers)
        float sy  = dot2bf(yr.x, ONE2,
                    dot2bf(yr.y, ONE2, dot2bf(yr.z, ONE2, dot2bf(yr.w, ONE2, 0.f))));
        float syy = dot2bf(yr.x, yr.x,
                    dot2bf(yr.y, yr.y, dot2bf(yr.z, yr.z, dot2bf(yr.w, yr.w, 0.f))));
        sy = gsum8(sy); syy = gsum8(syy);
        float my  = sy * (1.f / 64.f);
        float vy  = syy - sy * my;
        float svy = sqrtf(fmaxf(vy, 0.f));
        u4 o;
        o.x = cvtpk(acc[0], acc[1]); o.y = cvtpk(acc[2], acc[3]);
        o.z = cvtpk(acc[4], acc[5]); o.w = cvtpk(acc[6], acc[7]);
        // b for next layer: pearson(bf16 e1, t0)
        float sx  = dot2bf(o.x, ONE2,
                    dot2bf(o.y, ONE2, dot2bf(o.z, ONE2, dot2bf(o.w, ONE2, 0.f))));
        float sxx = dot2bf(o.x, o.x,
                    dot2bf(o.y, o.y, dot2bf(o.z, o.z, dot2bf(o.w, o.w, 0.f))));
        float sxy = dot2bf(o.x, yr.x,
                    dot2bf(o.y, yr.y, dot2bf(o.z, yr.z, dot2bf(o.w, yr.w, 0.f))));
        sx = gsum8(sx); sxx = gsum8(sxx); sxy = gsum8(sxy);
        float mx  = sx * (1.f / 64.f);
        float num = sxy - sx * my;
        float vx  = sxx - sx * mx;
        float den = sqrtf(fmaxf(vx, 0.f)) * svy;
        den = fmaxf(den, 1e-7f);
        float bn = num / den;
        if (valid) {
            if (j == 0) {
                f2 s2; s2.x = my; s2.y = svy;
                __builtin_nontemporal_store(s2, stats + rg);
                __builtin_nontemporal_store(bn, bbuf + rg);
            }
            __builtin_nontemporal_store(o, (u4*)(bfout + ro) + j);
            int lo = 0, hi = 0;
            lo = __builtin_amdgcn_cvt_pk_fp8_f32(acc[0] * SC, acc[1] * SC, lo, false);
            lo = __builtin_amdgcn_cvt_pk_fp8_f32(acc[2] * SC, acc[3] * SC, lo, true);
            hi = __builtin_amdgcn_cvt_pk_fp8_f32(acc[4] * SC, acc[5] * SC, hi, false);
            hi = __builtin_amdgcn_cvt_pk_fp8_f32(acc[6] * SC, acc[7] * SC, hi, true);
            u2 w8; w8.x = (unsigned)lo; w8.y = (unsigned)hi;
            __builtin_nontemporal_store(w8, (u2*)(f8out + (ro /*elems==bytes*64/64*/ )) + j);
        }
        return;
    }

    const float ob = 1.f - bcoef;
    float y0[8] = { bflo(yr.x), bfhi(yr.x), bflo(yr.y), bfhi(yr.y),
                    bflo(yr.z), bfhi(yr.z), bflo(yr.w), bfhi(yr.w) };
    float en[8];
    #pragma unroll
    for (int i = 0; i < 8; ++i) en[i] = bcoef * acc[i] + ob * y0[i];

    if (MODE == 1) {
        u4 o;
        o.x = cvtpk(en[0], en[1]); o.y = cvtpk(en[2], en[3]);
        o.z = cvtpk(en[4], en[5]); o.w = cvtpk(en[6], en[7]);
        // b for next layer: pearson(bf16 en, t0) with precomputed y-stats
        float sx  = dot2bf(o.x, ONE2,
                    dot2bf(o.y, ONE2, dot2bf(o.z, ONE2, dot2bf(o.w, ONE2, 0.f))));
        float sxx = dot2bf(o.x, o.x,
                    dot2bf(o.y, o.y, dot2bf(o.z, o.z, dot2bf(o.w, o.w, 0.f))));
        float sxy = dot2bf(o.x, yr.x,
                    dot2bf(o.y, yr.y, dot2bf(o.z, yr.z, dot2bf(o.w, yr.w, 0.f))));
        sx = gsum8(sx); sxx = gsum8(sxx); sxy = gsum8(sxy);
        float mx  = sx * (1.f / 64.f);
        float num = sxy - sx * st.x;
        float vx  = sxx - sx * mx;
        float den = sqrtf(fmaxf(vx, 0.f)) * st.y;
        den = fmaxf(den, 1e-7f);
        float bn = num / den;
        if (valid) {
            if (j == 0) __builtin_nontemporal_store(bn, bbuf + rg);
            if (SUM) {
                // S12 = e1row + en (bf16), drops one stream from MODE2
                u4 e1r = __builtin_nontemporal_load((const u4*)(e1in + ro) + j);
                u4 so;
                so.x = packbf(bflo(e1r.x) + en[0], bfhi(e1r.x) + en[1]);
                so.y = packbf(bflo(e1r.y) + en[2], bfhi(e1r.y) + en[3]);
                so.z = packbf(bflo(e1r.z) + en[4], bfhi(e1r.z) + en[5]);
                so.w = packbf(bflo(e1r.w) + en[6], bfhi(e1r.w) + en[7]);
                __builtin_nontemporal_store(so, (u4*)(bfout + ro) + j);
            } else {
                __builtin_nontemporal_store(o, (u4*)(bfout + ro) + j);
            }
            int lo = 0, hi = 0;
            lo = __builtin_amdgcn_cvt_pk_fp8_f32(en[0] * SC, en[1] * SC, lo, false);
            lo = __builtin_amdgcn_cvt_pk_fp8_f32(en[2] * SC, en[3] * SC, lo, true);
            hi = __builtin_amdgcn_cvt_pk_fp8_f32(en[4] * SC, en[5] * SC, hi, false);
            hi = __builtin_amdgcn_cvt_pk_fp8_f32(en[6] * SC, en[7] * SC, hi, true);
            u2 w8; w8.x = (unsigned)lo; w8.y = (unsigned)hi;
            __builtin_nontemporal_store(w8, (u2*)(f8out + ro) + j);
        }
    } else {
        // MODE 2: out = (t0 + s12 + e3 + en) / 5
        u4 xr  = __builtin_nontemporal_load((const u4*)(e3in + ro) + j);
        u4 s12 = __builtin_nontemporal_load((const u4*)(s12in + ro) + j);
        float s[8];
        s[0] = y0[0] + bflo(s12.x) + bflo(xr.x) + en[0];
        s[1] = y0[1] + bfhi(s12.x) + bfhi(xr.x) + en[1];
        s[2] = y0[2] + bflo(s12.y) + bflo(xr.y) + en[2];
        s[3] = y0[3] + bfhi(s12.y) + bfhi(xr.y) + en[3];
        s[4] = y0[4] + bflo(s12.z) + bflo(xr.z) + en[4];
        s[5] = y0[5] + bfhi(s12.z) + bfhi(xr.z) + en[5];
        s[6] = y0[6] + bflo(s12.w) + bflo(xr.w) + en[6];
        s[7] = y0[7] + bfhi(s12.w) + bfhi(xr.w) + en[7];
        if (valid) {
            f4 o0 = { s[0] * 0.2f, s[1] * 0.2f, s[2] * 0.2f, s[3] * 0.2f };
            f4 o1 = { s[4] * 0.2f, s[5] * 0.2f, s[6] * 0.2f, s[7] * 0.2f };
            f4* op = (f4*)(out + ro) + 2 * j;
            __builtin_nontemporal_store(o0, op);
            __builtin_nontemporal_store(o1, op + 1);
        }
    }
}

extern "C" void kernel_launch(void* const* d_in, const int* in_sizes, int n_in,
                              void* d_out, int out_size, void* d_ws, size_t ws_size,
                              hipStream_t stream) {
    const float* emb   = (const float*)d_in[0];
    const float* vals  = (const float*)d_in[1];
    const float* vals2 = (const float*)d_in[2];
    const int*   rows  = (const int*)d_in[3];
    const int*   cols  = (const int*)d_in[4];
    const int*   rows2 = (const int*)d_in[5];
    const int*   cols2 = (const int*)d_in[6];
    // n_layers = 3 (fixed for this problem)

    const int n    = in_sizes[0] / DIM;   // 300000
    const int nnz  = in_sizes[1];         // 4800000
    const int nnz2 = in_sizes[2];

    float* out = (float*)d_out;

    // ws: rp1|rp2|ST|BB | T0bf | E1bf(/E3bf) | S12 | T0f8 | FA | FB   (~180 MB)
    char*  ws       = (char*)d_ws;
    size_t rp_bytes = (((size_t)(n + 1) * sizeof(int)) + 255) & ~(size_t)255;
    size_t st_bytes = (((size_t)n * sizeof(f2)) + 255) & ~(size_t)255;
    size_t bb_bytes = (((size_t)n * sizeof(float)) + 255) & ~(size_t)255;
    size_t tb_bytes = (size_t)n * DIM * sizeof(unsigned short);  // 38.4 MB
    size_t f8_bytes = (size_t)n * DIM;                           // 19.2 MB
    int*   rp1 = (int*)ws;
    int*   rp2 = (int*)(ws + rp_bytes);
    f2*    ST  = (f2*)(ws + 2 * rp_bytes);
    float* BB  = (float*)(ws + 2 * rp_bytes + st_bytes);
    char*  p   = ws + 2 * rp_bytes + st_bytes + bb_bytes;
    unsigned short* T0  = (unsigned short*)p;              p += tb_bytes;
    unsigned short* E1  = (unsigned short*)p;              p += tb_bytes;  // reused as E3
    unsigned short* S12 = (unsigned short*)p;              p += tb_bytes;
    unsigned char*  T0F = (unsigned char*)p;               p += f8_bytes;
    unsigned char*  FA  = (unsigned char*)p;               p += f8_bytes;
    unsigned char*  FB  = (unsigned char*)p;               p += f8_bytes;
    unsigned short* E3  = E1;   // E1 (bf16) dead after layer 2 reads it

    const int tb = 256;
    build_row_ptr2_kernel<<<(2 * (n + 1) + tb - 1) / tb, tb, 0, stream>>>(
        rows, nnz, rows2, nnz2, n, rp1, rp2);

    const int n8 = n * DIM / 8;
    cvt_kernel<<<(n8 + tb - 1) / tb, tb, 0, stream>>>(emb, (unsigned int*)T0, T0F, n8);

    const int waves = (n + 7) / 8;            // 8 rows per wave
    const int grid  = (waves + 3) / 4;        // 4 waves per 256-thread block
    // L1: e1 = A1 @ T0f8 ; E1bf + FA ; y-stats ; b1
    layer_kernel<0, false><<<grid, tb, 0, stream>>>(T0, T0F, vals, cols, rp1, n,
                                                    E1, FA, E1, E1, S12, ST, BB, out);
    // L2: e2 from FA ; S12 = e1+e2 ; FB ; b2
    layer_kernel<1, true><<<grid, tb, 0, stream>>>(T0, FA, vals2, cols2, rp2, n,
                                                   S12, FB, E1, E1, S12, ST, BB, out);
    // L3: e3 from FB ; E3bf + FA ; b3
    layer_kernel<1, false><<<grid, tb, 0, stream>>>(T0, FB, vals2, cols2, rp2, n,
                                                    E3, FA, E1, E1, S12, ST, BB, out);
    // L4: e4 from FA ; out = (t0 + s12 + e3 + e4_blend)/5
    layer_kernel<2, false><<<grid, tb, 0, stream>>>(T0, FA, vals2, cols2, rp2, n,
                                                    E3, FA, E1, E3, S12, ST, BB, out);
}

// Round 12
// 456.679 us; speedup vs baseline: 8.2403x; 1.0388x over previous
//
#include <hip/hip_runtime.h>

#define DIM 64
#define SC  32.0f      // fp8 table scale (clears e4m3 subnormal band)
#define ISC 0.03125f   // 1/SC

typedef __attribute__((ext_vector_type(4))) float f4;
typedef __attribute__((ext_vector_type(2))) float f2;
typedef __attribute__((ext_vector_type(4))) unsigned int u4;
typedef __attribute__((ext_vector_type(2))) unsigned int u2;

#define ONE2 0x3f803f80u   // bf16 pair (1.0, 1.0)

// ---- bf16 helpers ----
__device__ __forceinline__ float bflo(unsigned u) { return __uint_as_float(u << 16); }
__device__ __forceinline__ float bfhi(unsigned u) { return __uint_as_float(u & 0xffff0000u); }
__device__ __forceinline__ unsigned bfr(float f) {
    unsigned u = __float_as_uint(f);
    return (u + 0x7fffu + ((u >> 16) & 1u)) >> 16;
}
__device__ __forceinline__ unsigned packbf(float e, float o) { return bfr(e) | (bfr(o) << 16); }
__device__ __forceinline__ unsigned cvtpk(float lo, float hi) {
    unsigned r;
    asm("v_cvt_pk_bf16_f32 %0, %1, %2" : "=v"(r) : "v"(lo), "v"(hi));
    return r;
}
__device__ __forceinline__ float dot2bf(unsigned a, unsigned b, float c) {
    float d;
    asm("v_dot2_f32_bf16 %0, %1, %2, %3" : "=v"(d) : "v"(a), "v"(b), "v"(c));
    return d;
}
__device__ __forceinline__ float gsum8(float v) {
    v += __shfl_xor(v, 1, 64);
    v += __shfl_xor(v, 2, 64);
    v += __shfl_xor(v, 4, 64);
    return v;
}

// Fused: rpA[r] = lower_bound(rowsA, r), rpB[r] = lower_bound(rowsB, r).
__global__ void build_row_ptr2_kernel(const int* __restrict__ rowsA, int nnzA,
                                      const int* __restrict__ rowsB, int nnzB,
                                      int n, int* __restrict__ rpA,
                                      int* __restrict__ rpB) {
    int i = blockIdx.x * blockDim.x + threadIdx.x;
    const int* rows; int nnz; int* rp; int r;
    if (i <= n) { rows = rowsA; nnz = nnzA; rp = rpA; r = i; }
    else {
        r = i - (n + 1);
        if (r > n) return;
        rows = rowsB; nnz = nnzB; rp = rpB;
    }
    int lo = 0, hi = nnz;
    while (lo < hi) {
        int mid = (lo + hi) >> 1;
        if (rows[mid] < r) lo = mid + 1; else hi = mid;
    }
    rp[r] = lo;
}

// f32 -> bf16 table + fp8(x*SC) table + per-row y-stats (my, sqrt(vy)).
// 8 elems per thread; 8 consecutive threads = one row.
__global__ void cvt_kernel(const float* __restrict__ in,
                           unsigned int* __restrict__ obf,
                           unsigned char* __restrict__ of8,
                           f2* __restrict__ stats, int n8) {
    int i = blockIdx.x * blockDim.x + threadIdx.x;
    if (i >= n8) return;
    const f4* p = (const f4*)in + 2 * (size_t)i;
    f4 a = p[0], b = p[1];
    u4 o;
    o.x = packbf(a.x, a.y); o.y = packbf(a.z, a.w);
    o.z = packbf(b.x, b.y); o.w = packbf(b.z, b.w);
    ((u4*)obf)[i] = o;
    int lo = 0, hi = 0;
    lo = __builtin_amdgcn_cvt_pk_fp8_f32(a.x * SC, a.y * SC, lo, false);
    lo = __builtin_amdgcn_cvt_pk_fp8_f32(a.z * SC, a.w * SC, lo, true);
    hi = __builtin_amdgcn_cvt_pk_fp8_f32(b.x * SC, b.y * SC, hi, false);
    hi = __builtin_amdgcn_cvt_pk_fp8_f32(b.z * SC, b.w * SC, hi, true);
    u2 w8; w8.x = (unsigned)lo; w8.y = (unsigned)hi;
    ((u2*)of8)[i] = w8;
    // y-stats from the bf16-rounded row (matches layer semantics)
    float sy  = dot2bf(o.x, ONE2,
                dot2bf(o.y, ONE2, dot2bf(o.z, ONE2, dot2bf(o.w, ONE2, 0.f))));
    float syy = dot2bf(o.x, o.x,
                dot2bf(o.y, o.y, dot2bf(o.z, o.z, dot2bf(o.w, o.w, 0.f))));
    sy = gsum8(sy); syy = gsum8(syy);
    float my  = sy * (1.f / 64.f);
    float vy  = syy - sy * my;
    float svy = sqrtf(fmaxf(vy, 0.f));
    if ((threadIdx.x & 7) == 0) {
        f2 s2; s2.x = my; s2.y = svy;
        __builtin_nontemporal_store(s2, stats + (i >> 3));
    }
}

// One ROW per 8-lane group (8 rows/wave); lane j owns dims 8j..8j+7.
// Gathers read the fp8 (x*32) table: 64B rows, dwordx2 per lane.
// MODE 0: e1 = A1 @ T0f8 -> f8out only; b1 -> bbuf (y-side from fp8 T0f8)
// MODE 1: prop = A2@gtab; en = b*prop+(1-b)*t0; b_next -> bbuf; f8out = fp8(en)
//         SUM: also S12 = dq(gtab row) + en -> bfout (bf16)
// MODE 2: en as MODE1; out = (t0 + s12 + dq(gtab row) + en)/5  (f32)
template <int MODE, bool SUM>
__global__ __launch_bounds__(256) void layer_kernel(
    const unsigned short* __restrict__ t0,
    const unsigned char*  __restrict__ gtab,
    const float* __restrict__ vals, const int* __restrict__ cols,
    const int* __restrict__ rp, int n,
    unsigned short* __restrict__ bfout,
    unsigned char*  __restrict__ f8out,
    const unsigned short* __restrict__ s12in,
    f2* __restrict__ stats, float* __restrict__ bbuf,
    float* __restrict__ out)
{
    const int tid  = threadIdx.x;
    const int lane = tid & 63;
    const int j    = lane & 7;
    const int wave = blockIdx.x * (blockDim.x >> 6) + (tid >> 6);
    const int rowg = wave * 8 + (lane >> 3);
    const bool valid = rowg < n;
    const int rg   = valid ? rowg : n - 1;

    const int start = rp[rg];
    const int end   = rp[rg + 1];
    const int len   = valid ? (end - start) : 0;
    const int b0    = start & ~1;
    const int doff  = b0 - start;

    int ml = len;
    ml = max(ml, __shfl_xor(ml, 8, 64));
    ml = max(ml, __shfl_xor(ml, 16, 64));
    ml = max(ml, __shfl_xor(ml, 32, 64));
    const int steps = (ml + 8) >> 3;

    const unsigned joff8 = (unsigned)(j << 3);
    const size_t ro = (size_t)rg << 6;

    // early row-stream loads (hide under main loop)
    float bcoef = 0.f;
    if (MODE != 0) bcoef = __builtin_nontemporal_load(bbuf + rg);
    u4 yr = {};
    if (MODE != 0) yr = __builtin_nontemporal_load((const u4*)(t0 + ro) + j);
    f2 st = {};
    if (MODE != 2) st = __builtin_nontemporal_load(stats + rg);
    // own row of the gather table (L2-hot): e1 (SUM), e3 (MODE2), y (MODE0)
    u2 gr = {};
    if (MODE == 0 || SUM || MODE == 2)
        gr = *(const u2*)(gtab + ro + joff8);

    f2 a01 = {0.f, 0.f}, a23 = {0.f, 0.f}, a45 = {0.f, 0.f}, a67 = {0.f, 0.f};

    for (int s = 0; s < steps; ++s) {
        const int k = b0 + (s << 3);
        u2 c01 = __builtin_nontemporal_load((const u2*)(cols + k));
        u2 c23 = __builtin_nontemporal_load((const u2*)(cols + k + 2));
        u2 c45 = __builtin_nontemporal_load((const u2*)(cols + k + 4));
        u2 c67 = __builtin_nontemporal_load((const u2*)(cols + k + 6));
        f2 v01 = __builtin_nontemporal_load((const f2*)(vals + k));
        f2 v23 = __builtin_nontemporal_load((const f2*)(vals + k + 2));
        f2 v45 = __builtin_nontemporal_load((const f2*)(vals + k + 4));
        f2 v67 = __builtin_nontemporal_load((const f2*)(vals + k + 6));
        const int rel = (s << 3) + doff;
        bool ok0 = (unsigned)(rel)     < (unsigned)len;
        bool ok1 = (unsigned)(rel + 1) < (unsigned)len;
        bool ok2 = (unsigned)(rel + 2) < (unsigned)len;
        bool ok3 = (unsigned)(rel + 3) < (unsigned)len;
        bool ok4 = (unsigned)(rel + 4) < (unsigned)len;
        bool ok5 = (unsigned)(rel + 5) < (unsigned)len;
        bool ok6 = (unsigned)(rel + 6) < (unsigned)len;
        bool ok7 = (unsigned)(rel + 7) < (unsigned)len;
        unsigned cc0 = ok0 ? (unsigned)c01.x : 0u;
        unsigned cc1 = ok1 ? (unsigned)c01.y : 0u;
        unsigned cc2 = ok2 ? (unsigned)c23.x : 0u;
        unsigned cc3 = ok3 ? (unsigned)c23.y : 0u;
        unsigned cc4 = ok4 ? (unsigned)c45.x : 0u;
        unsigned cc5 = ok5 ? (unsigned)c45.y : 0u;
        unsigned cc6 = ok6 ? (unsigned)c67.x : 0u;
        unsigned cc7 = ok7 ? (unsigned)c67.y : 0u;
        // 8 independent 8B gathers in flight
        u2 g0 = *(const u2*)(gtab + ((cc0 << 6) + joff8));
        u2 g1 = *(const u2*)(gtab + ((cc1 << 6) + joff8));
        u2 g2 = *(const u2*)(gtab + ((cc2 << 6) + joff8));
        u2 g3 = *(const u2*)(gtab + ((cc3 << 6) + joff8));
        u2 g4 = *(const u2*)(gtab + ((cc4 << 6) + joff8));
        u2 g5 = *(const u2*)(gtab + ((cc5 << 6) + joff8));
        u2 g6 = *(const u2*)(gtab + ((cc6 << 6) + joff8));
        u2 g7 = *(const u2*)(gtab + ((cc7 << 6) + joff8));
        float w0 = ok0 ? v01.x : 0.f;
        float w1 = ok1 ? v01.y : 0.f;
        float w2 = ok2 ? v23.x : 0.f;
        float w3 = ok3 ? v23.y : 0.f;
        float w4 = ok4 ? v45.x : 0.f;
        float w5 = ok5 ? v45.y : 0.f;
        float w6 = ok6 ? v67.x : 0.f;
        float w7 = ok7 ? v67.y : 0.f;
#define CONS(gg, ww) {                                                        \
        f2 wv; wv.x = (ww); wv.y = (ww);                                      \
        f2 p0 = __builtin_amdgcn_cvt_pk_f32_fp8((int)gg.x, false);            \
        f2 p1 = __builtin_amdgcn_cvt_pk_f32_fp8((int)gg.x, true);             \
        f2 p2 = __builtin_amdgcn_cvt_pk_f32_fp8((int)gg.y, false);            \
        f2 p3 = __builtin_amdgcn_cvt_pk_f32_fp8((int)gg.y, true);             \
        a01 += wv * p0; a23 += wv * p1; a45 += wv * p2; a67 += wv * p3;       \
    }
        CONS(g0, w0) CONS(g1, w1) CONS(g2, w2) CONS(g3, w3)
        CONS(g4, w4) CONS(g5, w5) CONS(g6, w6) CONS(g7, w7)
#undef CONS
    }

    float acc[8] = { a01.x * ISC, a01.y * ISC, a23.x * ISC, a23.y * ISC,
                     a45.x * ISC, a45.y * ISC, a67.x * ISC, a67.y * ISC };

    // dequant own gather-table row (e1 / e3 / y0f8)
    f2 q0 = __builtin_amdgcn_cvt_pk_f32_fp8((int)gr.x, false);
    f2 q1 = __builtin_amdgcn_cvt_pk_f32_fp8((int)gr.x, true);
    f2 q2 = __builtin_amdgcn_cvt_pk_f32_fp8((int)gr.y, false);
    f2 q3 = __builtin_amdgcn_cvt_pk_f32_fp8((int)gr.y, true);
    float grf[8] = { q0.x * ISC, q0.y * ISC, q1.x * ISC, q1.y * ISC,
                     q2.x * ISC, q2.y * ISC, q3.x * ISC, q3.y * ISC };

    if (MODE == 0) {
        u4 o;
        o.x = cvtpk(acc[0], acc[1]); o.y = cvtpk(acc[2], acc[3]);
        o.z = cvtpk(acc[4], acc[5]); o.w = cvtpk(acc[6], acc[7]);
        // b1 = pearson(bf16 e1, y) with y from the fp8 t0 table
        unsigned yb0 = cvtpk(grf[0], grf[1]), yb1 = cvtpk(grf[2], grf[3]);
        unsigned yb2 = cvtpk(grf[4], grf[5]), yb3 = cvtpk(grf[6], grf[7]);
        float sx  = dot2bf(o.x, ONE2,
                    dot2bf(o.y, ONE2, dot2bf(o.z, ONE2, dot2bf(o.w, ONE2, 0.f))));
        float sxx = dot2bf(o.x, o.x,
                    dot2bf(o.y, o.y, dot2bf(o.z, o.z, dot2bf(o.w, o.w, 0.f))));
        float sxy = dot2bf(o.x, yb0,
                    dot2bf(o.y, yb1, dot2bf(o.z, yb2, dot2bf(o.w, yb3, 0.f))));
        sx = gsum8(sx); sxx = gsum8(sxx); sxy = gsum8(sxy);
        float mx  = sx * (1.f / 64.f);
        float num = sxy - sx * st.x;
        float vx  = sxx - sx * mx;
        float den = sqrtf(fmaxf(vx, 0.f)) * st.y;
        den = fmaxf(den, 1e-7f);
        float bn = num / den;
        if (valid) {
            if (j == 0) __builtin_nontemporal_store(bn, bbuf + rg);
            int lo = 0, hi = 0;
            lo = __builtin_amdgcn_cvt_pk_fp8_f32(acc[0] * SC, acc[1] * SC, lo, false);
            lo = __builtin_amdgcn_cvt_pk_fp8_f32(acc[2] * SC, acc[3] * SC, lo, true);
            hi = __builtin_amdgcn_cvt_pk_fp8_f32(acc[4] * SC, acc[5] * SC, hi, false);
            hi = __builtin_amdgcn_cvt_pk_fp8_f32(acc[6] * SC, acc[7] * SC, hi, true);
            u2 w8; w8.x = (unsigned)lo; w8.y = (unsigned)hi;
            __builtin_nontemporal_store(w8, (u2*)(f8out + ro) + j);
        }
        return;
    }

    const float ob = 1.f - bcoef;
    float y0[8] = { bflo(yr.x), bfhi(yr.x), bflo(yr.y), bfhi(yr.y),
                    bflo(yr.z), bfhi(yr.z), bflo(yr.w), bfhi(yr.w) };
    float en[8];
    #pragma unroll
    for (int i = 0; i < 8; ++i) en[i] = bcoef * acc[i] + ob * y0[i];

    if (MODE == 1) {
        u4 o;
        o.x = cvtpk(en[0], en[1]); o.y = cvtpk(en[2], en[3]);
        o.z = cvtpk(en[4], en[5]); o.w = cvtpk(en[6], en[7]);
        // b_next = pearson(bf16 en, t0) with precomputed y-stats
        float sx  = dot2bf(o.x, ONE2,
                    dot2bf(o.y, ONE2, dot2bf(o.z, ONE2, dot2bf(o.w, ONE2, 0.f))));
        float sxx = dot2bf(o.x, o.x,
                    dot2bf(o.y, o.y, dot2bf(o.z, o.z, dot2bf(o.w, o.w, 0.f))));
        float sxy = dot2bf(o.x, yr.x,
                    dot2bf(o.y, yr.y, dot2bf(o.z, yr.z, dot2bf(o.w, yr.w, 0.f))));
        sx = gsum8(sx); sxx = gsum8(sxx); sxy = gsum8(sxy);
        float mx  = sx * (1.f / 64.f);
        float num = sxy - sx * st.x;
        float vx  = sxx - sx * mx;
        float den = sqrtf(fmaxf(vx, 0.f)) * st.y;
        den = fmaxf(den, 1e-7f);
        float bn = num / den;
        if (valid) {
            if (j == 0) __builtin_nontemporal_store(bn, bbuf + rg);
            if (SUM) {
                // S12 = dq(e1 fp8) + en  (bf16)
                u4 so;
                so.x = packbf(grf[0] + en[0], grf[1] + en[1]);
                so.y = packbf(grf[2] + en[2], grf[3] + en[3]);
                so.z = packbf(grf[4] + en[4], grf[5] + en[5]);
                so.w = packbf(grf[6] + en[6], grf[7] + en[7]);
                __builtin_nontemporal_store(so, (u4*)(bfout + ro) + j);
            }
            int lo = 0, hi = 0;
            lo = __builtin_amdgcn_cvt_pk_fp8_f32(en[0] * SC, en[1] * SC, lo, false);
            lo = __builtin_amdgcn_cvt_pk_fp8_f32(en[2] * SC, en[3] * SC, lo, true);
            hi = __builtin_amdgcn_cvt_pk_fp8_f32(en[4] * SC, en[5] * SC, hi, false);
            hi = __builtin_amdgcn_cvt_pk_fp8_f32(en[6] * SC, en[7] * SC, hi, true);
            u2 w8; w8.x = (unsigned)lo; w8.y = (unsigned)hi;
            __builtin_nontemporal_store(w8, (u2*)(f8out + ro) + j);
        }
    } else {
        // MODE 2: out = (t0 + s12 + dq(e3 fp8) + en) / 5
        u4 s12 = __builtin_nontemporal_load((const u4*)(s12in + ro) + j);
        float s[8];
        s[0] = y0[0] + bflo(s12.x) + grf[0] + en[0];
        s[1] = y0[1] + bfhi(s12.x) + grf[1] + en[1];
        s[2] = y0[2] + bflo(s12.y) + grf[2] + en[2];
        s[3] = y0[3] + bfhi(s12.y) + grf[3] + en[3];
        s[4] = y0[4] + bflo(s12.z) + grf[4] + en[4];
        s[5] = y0[5] + bfhi(s12.z) + grf[5] + en[5];
        s[6] = y0[6] + bflo(s12.w) + grf[6] + en[6];
        s[7] = y0[7] + bfhi(s12.w) + grf[7] + en[7];
        if (valid) {
            f4 o0 = { s[0] * 0.2f, s[1] * 0.2f, s[2] * 0.2f, s[3] * 0.2f };
            f4 o1 = { s[4] * 0.2f, s[5] * 0.2f, s[6] * 0.2f, s[7] * 0.2f };
            f4* op = (f4*)(out + ro) + 2 * j;
            __builtin_nontemporal_store(o0, op);
            __builtin_nontemporal_store(o1, op + 1);
        }
    }
}

extern "C" void kernel_launch(void* const* d_in, const int* in_sizes, int n_in,
                              void* d_out, int out_size, void* d_ws, size_t ws_size,
                              hipStream_t stream) {
    const float* emb   = (const float*)d_in[0];
    const float* vals  = (const float*)d_in[1];
    const float* vals2 = (const float*)d_in[2];
    const int*   rows  = (const int*)d_in[3];
    const int*   cols  = (const int*)d_in[4];
    const int*   rows2 = (const int*)d_in[5];
    const int*   cols2 = (const int*)d_in[6];
    // n_layers = 3 (fixed for this problem)

    const int n    = in_sizes[0] / DIM;   // 300000
    const int nnz  = in_sizes[1];         // 4800000
    const int nnz2 = in_sizes[2];

    float* out = (float*)d_out;

    // ws: rp1|rp2|ST|BB | T0bf | S12 | T0f8 | FA | FB   (~140 MB)
    char*  ws       = (char*)d_ws;
    size_t rp_bytes = (((size_t)(n + 1) * sizeof(int)) + 255) & ~(size_t)255;
    size_t st_bytes = (((size_t)n * sizeof(f2)) + 255) & ~(size_t)255;
    size_t bb_bytes = (((size_t)n * sizeof(float)) + 255) & ~(size_t)255;
    size_t tb_bytes = (size_t)n * DIM * sizeof(unsigned short);  // 38.4 MB
    size_t f8_bytes = (size_t)n * DIM;                           // 19.2 MB
    int*   rp1 = (int*)ws;
    int*   rp2 = (int*)(ws + rp_bytes);
    f2*    ST  = (f2*)(ws + 2 * rp_bytes);
    float* BB  = (float*)(ws + 2 * rp_bytes + st_bytes);
    char*  p   = ws + 2 * rp_bytes + st_bytes + bb_bytes;
    unsigned short* T0  = (unsigned short*)p;              p += tb_bytes;
    unsigned short* S12 = (unsigned short*)p;              p += tb_bytes;
    unsigned char*  T0F = (unsigned char*)p;               p += f8_bytes;
    unsigned char*  FA  = (unsigned char*)p;               p += f8_bytes;
    unsigned char*  FB  = (unsigned char*)p;               p += f8_bytes;

    const int tb = 256;
    build_row_ptr2_kernel<<<(2 * (n + 1) + tb - 1) / tb, tb, 0, stream>>>(
        rows, nnz, rows2, nnz2, n, rp1, rp2);

    const int n8 = n * DIM / 8;
    cvt_kernel<<<(n8 + tb - 1) / tb, tb, 0, stream>>>(emb, (unsigned int*)T0, T0F, ST, n8);

    const int waves = (n + 7) / 8;            // 8 rows per wave
    const int grid  = (waves + 3) / 4;        // 4 waves per 256-thread block
    // L1: e1 = A1 @ T0f8 -> FA ; b1
    layer_kernel<0, false><<<grid, tb, 0, stream>>>(T0, T0F, vals, cols, rp1, n,
                                                    S12, FA, S12, ST, BB, out);
    // L2: e2 from FA ; S12 = dq(FA row) + e2 ; FB ; b2
    layer_kernel<1, true><<<grid, tb, 0, stream>>>(T0, FA, vals2, cols2, rp2, n,
                                                   S12, FB, S12, ST, BB, out);
    // L3: e3 from FB -> FA ; b3
    layer_kernel<1, false><<<grid, tb, 0, stream>>>(T0, FB, vals2, cols2, rp2, n,
                                                    S12, FA, S12, ST, BB, out);
    // L4: e4 from FA ; out = (t0 + s12 + dq(FA row) + e4_blend)/5
    layer_kernel<2, false><<<grid, tb, 0, stream>>>(T0, FA, vals2, cols2, rp2, n,
                                                    S12, FA, S12, ST, BB, out);
}